// Round 1
// baseline (1317.950 us; speedup 1.0000x reference)
//
#include <hip/hip_runtime.h>
#include <math.h>

#define DM 96
#define DE 192
#define LL 2304
#define NS 16
#define RK 6
#define NC 38   // RK + 2*NS

__device__ __forceinline__ float silu_f(float x){ return x / (1.f + __expf(-x)); }
__device__ __forceinline__ float softplus_f(float x){ return (x > 20.f) ? x : log1pf(__expf(x)); }

// xs[b,k,d,l] = xconv[b,d,dir_map(k,l)]
__device__ __forceinline__ int dir_map(int k, int l){
    switch(k){
      case 0: return l;
      case 1: return (l % 48) * 48 + l / 48;
      case 2: return 2303 - l;
      default: { int lr = 2303 - l; return (lr % 48) * 48 + lr / 48; }
    }
}

// K1: 1x1 conv in (96 -> 384), split into x1raw (first 192) and z=silu (last 192)
__global__ __launch_bounds__(384) void k1_conv_in(const float* __restrict__ x,
    const float* __restrict__ in_w, const float* __restrict__ in_b,
    float* __restrict__ x1raw, float* __restrict__ z){
  __shared__ float xv[DM*16];
  int tile = blockIdx.x;
  int b = tile / 144;
  int pos0 = (tile % 144) * 16;
  int tid = threadIdx.x;
  for (int i = tid; i < DM*16; i += 384){
    int c = i >> 4, p = i & 15;
    xv[c*16 + p] = x[(b*DM + c)*LL + pos0 + p];
  }
  __syncthreads();
  float acc[16];
  #pragma unroll
  for (int p=0;p<16;p++) acc[p] = in_b[tid];
  for (int c=0;c<DM;c++){
    float w = in_w[tid*DM + c];
    #pragma unroll
    for (int p=0;p<16;p++) acc[p] = fmaf(w, xv[c*16+p], acc[p]);
  }
  if (tid < DE){
    #pragma unroll
    for (int p=0;p<16;p++) x1raw[(b*DE + tid)*LL + pos0 + p] = acc[p];
  } else {
    int zc = tid - DE;
    #pragma unroll
    for (int p=0;p<16;p++) z[(b*DE + zc)*LL + pos0 + p] = silu_f(acc[p]);
  }
}

// K2: depthwise 3x3 SAME + bias + silu
__global__ __launch_bounds__(256) void k2_dwconv(const float* __restrict__ x1raw,
    const float* __restrict__ dw_w, const float* __restrict__ dw_b,
    float* __restrict__ xconv){
  int idx = blockIdx.x*256 + threadIdx.x;  // over B*DE*LL = 884736
  int pos = idx % LL; int bd = idx / LL;
  int d = bd % DE;
  int h = pos / 48, w = pos % 48;
  float acc = dw_b[d];
  #pragma unroll
  for (int kh=0;kh<3;kh++){
    int hh = h + kh - 1;
    if (hh < 0 || hh >= 48) continue;
    #pragma unroll
    for (int kw=0;kw<3;kw++){
      int ww_ = w + kw - 1;
      if (ww_ < 0 || ww_ >= 48) continue;
      acc = fmaf(dw_w[d*9 + kh*3 + kw], x1raw[bd*LL + hh*48 + ww_], acc);
    }
  }
  xconv[idx] = silu_f(acc);
}

// K3: x_dbl projection + dt projection + softplus; emit delta (b,k,d,l), Bs/Cs (b,k,l,16)
__global__ __launch_bounds__(64) void k3_proj(const float* __restrict__ xconv,
    const float* __restrict__ x_proj_w, const float* __restrict__ dt_w,
    const float* __restrict__ dt_b, float* __restrict__ delta,
    float* __restrict__ Bs, float* __restrict__ Cs){
  int bk = blockIdx.x / 36;
  int tile = blockIdx.x % 36;
  int b = bk >> 2, k = bk & 3;
  int l = tile*64 + threadIdx.x;
  float acc[NC];
  #pragma unroll
  for (int c=0;c<NC;c++) acc[c]=0.f;
  int pos = dir_map(k, l);
  const float* xc_base = xconv + b*DE*LL + pos;
  const float* wbase = x_proj_w + k*NC*DE;
  for (int d=0; d<DE; d++){
    float u = xc_base[d*LL];
    #pragma unroll
    for (int c=0;c<NC;c++) acc[c] = fmaf(u, wbase[c*DE + d], acc[c]);
  }
  const float* dwb = dt_w + k*DE*RK;
  const float* dbb = dt_b + k*DE;
  float* dout = delta + (bk*DE)*LL + l;
  for (int d=0; d<DE; d++){
    float t = dbb[d];
    #pragma unroll
    for (int r=0;r<RK;r++) t = fmaf(acc[r], dwb[d*RK + r], t);
    dout[d*LL] = softplus_f(t);
  }
  float* bptr = Bs + (bk*LL + l)*NS;
  float* cptr = Cs + (bk*LL + l)*NS;
  #pragma unroll
  for (int n=0;n<NS;n++){ bptr[n] = acc[RK+n]; cptr[n] = acc[RK+NS+n]; }
}

// K4: selective scan. One lane per (b,k,d,n) chain; 16-lane shuffle reduce over n.
__global__ __launch_bounds__(64) void k4_scan(const float* __restrict__ xconv,
    const float* __restrict__ delta, const float* __restrict__ Bs,
    const float* __restrict__ Cs, const float* __restrict__ A_logs,
    const float* __restrict__ Ds, float* __restrict__ out_y){
  int tid = threadIdx.x;
  int grp = blockIdx.x*4 + (tid >> 4);   // [0, 1536)
  int n = tid & 15;
  int b = grp / (4*DE);
  int kd = grp % (4*DE);
  int k = kd / DE;
  int d = kd % DE;
  int bk = b*4 + k;
  float A  = -__expf(A_logs[(k*DE + d)*NS + n]);
  float Dv = Ds[k*DE + d];
  const float* dptr = delta + (bk*DE + d)*LL;
  const float* uptr = xconv + (b*DE + d)*LL;
  const float* bptr = Bs + bk*LL*NS + n;
  const float* cptr = Cs + bk*LL*NS + n;
  float* optr = out_y + (bk*DE + d)*LL;
  float h = 0.f;
  #pragma unroll 4
  for (int l=0; l<LL; l++){
    float dl = dptr[l];
    float u  = uptr[dir_map(k, l)];
    float Bv = bptr[l*NS];
    float Cv = cptr[l*NS];
    float dA = __expf(dl * A);
    h = fmaf(h, dA, dl * u * Bv);
    float py = h * Cv;
    py += __shfl_xor(py, 1);
    py += __shfl_xor(py, 2);
    py += __shfl_xor(py, 4);
    py += __shfl_xor(py, 8);
    if (n == 0) optr[l] = fmaf(Dv, u, py);
  }
}

// K5: combine 4 directions + channel LayerNorm per pixel
__global__ __launch_bounds__(192) void k5_combine_ln(const float* __restrict__ out_y,
    const float* __restrict__ onw, const float* __restrict__ onb,
    float* __restrict__ y_ln){
  int p = blockIdx.x;          // b*LL + pos
  int b = p / LL, pos = p % LL;
  int h = pos / 48, w = pos % 48;
  int wpos = w*48 + h;
  int d = threadIdx.x;
  const float* base = out_y + b*4*DE*LL;
  float val = base[(0*DE + d)*LL + pos]
            + base[(2*DE + d)*LL + (2303 - pos)]
            + base[(1*DE + d)*LL + wpos]
            + base[(3*DE + d)*LL + (2303 - wpos)];
  float v = val, v2 = val*val;
  for (int off=32; off>0; off>>=1){ v += __shfl_down(v, off); v2 += __shfl_down(v2, off); }
  __shared__ float sA[3], sB[3];
  __shared__ float sMu, sR;
  int lane = d & 63, wid = d >> 6;
  if (lane == 0){ sA[wid] = v; sB[wid] = v2; }
  __syncthreads();
  if (d == 0){
    float s = sA[0]+sA[1]+sA[2], s2 = sB[0]+sB[1]+sB[2];
    float mu = s / DE;
    float var = s2 / DE - mu*mu;
    sMu = mu; sR = rsqrtf(var + 1e-5f);
  }
  __syncthreads();
  y_ln[(b*DE + d)*LL + pos] = (val - sMu)*sR*onw[d] + onb[d];
}

// K6a: xc[b,d] = mean over pixels of y_ln
__global__ __launch_bounds__(256) void k6a_xc(const float* __restrict__ y_ln, float* __restrict__ xc){
  int row = blockIdx.x; // b*DE + d
  const float* p = y_ln + row*LL;
  float s = 0.f;
  for (int i = threadIdx.x; i < LL; i += 256) s += p[i];
  for (int off=32; off>0; off>>=1) s += __shfl_down(s, off);
  __shared__ float sw[4];
  int lane = threadIdx.x & 63, wid = threadIdx.x >> 6;
  if (lane==0) sw[wid] = s;
  __syncthreads();
  if (threadIdx.x==0) xc[row] = (sw[0]+sw[1]+sw[2]+sw[3]) * (1.f/LL);
}

// K6b: entire channel core in one block. wave = (b,k); lane -> (dc, n)
__global__ __launch_bounds__(256) void k6b_channel(const float* __restrict__ xc,
    const float* __restrict__ cin_w, const float* __restrict__ cin_b,
    const float* __restrict__ cout_w, const float* __restrict__ cout_b,
    const float* __restrict__ xc_proj_w, const float* __restrict__ dtc_w,
    const float* __restrict__ dtc_b, const float* __restrict__ Ac_logs,
    const float* __restrict__ Dsc, const float* __restrict__ cn_w,
    const float* __restrict__ cn_b, float* __restrict__ cvec){
  __shared__ float xcs[2][DE];
  __shared__ float outc[2][2][4][DE];
  __shared__ float ycs[2][DE];
  __shared__ float stats[2][2];
  int tid = threadIdx.x;
  for (int i = tid; i < 2*DE; i += 256) xcs[i/DE][i%DE] = xc[i];
  __syncthreads();
  int wv = tid >> 6;
  int b = wv >> 1, k = wv & 1;
  int lane = tid & 63;
  int dc = (lane >> 4) & 3, n = lane & 15;
  float EW[4], Bw[4], Cw[4];
  #pragma unroll
  for (int j=0;j<4;j++){
    float e = 0.f;
    #pragma unroll
    for (int r=0;r<RK;r++) e = fmaf(dtc_w[(k*4+dc)*RK + r], xc_proj_w[(k*NC + r)*4 + j], e);
    EW[j] = e;
    Bw[j] = xc_proj_w[(k*NC + RK + n)*4 + j];
    Cw[j] = xc_proj_w[(k*NC + RK + NS + n)*4 + j];
  }
  float A  = -__expf(Ac_logs[(k*4+dc)*NS + n]);
  float Dv = Dsc[k*4+dc];
  float dtb = dtc_b[k*4+dc];
  float ciw0=cin_w[0], ciw1=cin_w[1], ciw2=cin_w[2], ciw3=cin_w[3];
  float cib0=cin_b[0], cib1=cin_b[1], cib2=cin_b[2], cib3=cin_b[3];
  float h = 0.f;
  for (int lc=0; lc<DE; lc++){
    int lp = k ? (191 - lc) : lc;
    float xv = xcs[b][lp];
    float xs0 = fmaf(xv, ciw0, cib0);
    float xs1 = fmaf(xv, ciw1, cib1);
    float xs2 = fmaf(xv, ciw2, cib2);
    float xs3 = fmaf(xv, ciw3, cib3);
    float dt = dtb + xs0*EW[0] + xs1*EW[1] + xs2*EW[2] + xs3*EW[3];
    float dl = softplus_f(dt);
    float Bv = xs0*Bw[0] + xs1*Bw[1] + xs2*Bw[2] + xs3*Bw[3];
    float Cv = xs0*Cw[0] + xs1*Cw[1] + xs2*Cw[2] + xs3*Cw[3];
    float u = (dc==0)?xs0:((dc==1)?xs1:((dc==2)?xs2:xs3));
    float dA = __expf(dl * A);
    h = fmaf(h, dA, dl*u*Bv);
    float py = h * Cv;
    py += __shfl_xor(py, 1);
    py += __shfl_xor(py, 2);
    py += __shfl_xor(py, 4);
    py += __shfl_xor(py, 8);
    if (n==0) outc[b][k][dc][lc] = fmaf(Dv, u, py);
  }
  __syncthreads();
  float co0=cout_w[0], co1=cout_w[1], co2=cout_w[2], co3=cout_w[3], cob=cout_b[0];
  for (int i = tid; i < 2*DE; i += 256){
    int bb = i / DE, lc = i % DE;
    float yv = cob
      + co0*(outc[bb][0][0][lc] + outc[bb][1][0][191-lc])
      + co1*(outc[bb][0][1][lc] + outc[bb][1][1][191-lc])
      + co2*(outc[bb][0][2][lc] + outc[bb][1][2][191-lc])
      + co3*(outc[bb][0][3][lc] + outc[bb][1][3][191-lc]);
    ycs[bb][lc] = yv;
  }
  __syncthreads();
  if (tid < 2){
    float s=0.f, s2=0.f;
    for (int lc=0; lc<DE; lc++){ float v=ycs[tid][lc]; s+=v; s2+=v*v; }
    float mu = s/DE; float var = s2/DE - mu*mu;
    stats[tid][0]=mu; stats[tid][1]=rsqrtf(var+1e-5f);
  }
  __syncthreads();
  for (int i = tid; i < 2*DE; i += 256){
    int bb = i / DE, lc = i % DE;
    cvec[i] = (ycs[bb][lc] - stats[bb][0]) * stats[bb][1] * cn_w[lc] + cn_b[lc];
  }
}

// K7: out = conv1x1(y_ln * c * z), 192 -> 96
__global__ __launch_bounds__(256) void k7_out(const float* __restrict__ y_ln,
    const float* __restrict__ cvec, const float* __restrict__ z,
    const float* __restrict__ out_w, const float* __restrict__ out_b,
    float* __restrict__ outp){
  __shared__ float t[DE*16];
  int tile = blockIdx.x;
  int b = tile / 144;
  int pos0 = (tile % 144) * 16;
  int tid = threadIdx.x;
  for (int i = tid; i < DE*16; i += 256){
    int c = i >> 4, p = i & 15;
    int gi = (b*DE + c)*LL + pos0 + p;
    t[c*16 + p] = y_ln[gi] * cvec[b*DE + c] * z[gi];
  }
  __syncthreads();
  for (int j = tid; j < DM*16; j += 256){
    int o = j >> 4, p = j & 15;
    float acc = out_b[o];
    const float* wr = out_w + o*DE;
    #pragma unroll 4
    for (int c=0;c<DE;c++) acc = fmaf(wr[c], t[c*16+p], acc);
    outp[(b*DM + o)*LL + pos0 + p] = acc;
  }
}

extern "C" void kernel_launch(void* const* d_in, const int* in_sizes, int n_in,
                              void* d_out, int out_size, void* d_ws, size_t ws_size,
                              hipStream_t stream){
  const float* x        = (const float*)d_in[0];
  const float* in_w     = (const float*)d_in[1];
  const float* in_b     = (const float*)d_in[2];
  const float* dw_w     = (const float*)d_in[3];
  const float* dw_b     = (const float*)d_in[4];
  const float* x_proj_w = (const float*)d_in[5];
  const float* dt_w     = (const float*)d_in[6];
  const float* dt_b     = (const float*)d_in[7];
  const float* A_logs   = (const float*)d_in[8];
  const float* Ds       = (const float*)d_in[9];
  const float* onw      = (const float*)d_in[10];
  const float* onb      = (const float*)d_in[11];
  const float* cin_w    = (const float*)d_in[12];
  const float* cin_b    = (const float*)d_in[13];
  const float* cout_w   = (const float*)d_in[14];
  const float* cout_b   = (const float*)d_in[15];
  const float* xc_proj_w= (const float*)d_in[16];
  const float* dtc_w    = (const float*)d_in[17];
  const float* dtc_b    = (const float*)d_in[18];
  const float* Ac_logs  = (const float*)d_in[19];
  const float* Dsc      = (const float*)d_in[20];
  const float* cn_w     = (const float*)d_in[21];
  const float* cn_b     = (const float*)d_in[22];
  const float* out_w    = (const float*)d_in[23];
  const float* out_b    = (const float*)d_in[24];

  float* ws = (float*)d_ws;
  float* x1raw = ws;  ws += 2*DE*LL;
  float* zbuf  = ws;  ws += 2*DE*LL;
  float* xconv = ws;  ws += 2*DE*LL;
  float* delta = ws;  ws += 2*4*DE*LL;
  float* Bsb   = ws;  ws += 2*4*LL*NS;
  float* Csb   = ws;  ws += 2*4*LL*NS;
  float* outy  = ws;  ws += 2*4*DE*LL;
  float* yln   = ws;  ws += 2*DE*LL;
  float* xcb   = ws;  ws += 2*DE;
  float* cvec  = ws;  ws += 2*DE;

  hipLaunchKernelGGL(k1_conv_in, dim3(288), dim3(384), 0, stream, x, in_w, in_b, x1raw, zbuf);
  hipLaunchKernelGGL(k2_dwconv, dim3(3456), dim3(256), 0, stream, x1raw, dw_w, dw_b, xconv);
  hipLaunchKernelGGL(k3_proj, dim3(288), dim3(64), 0, stream, xconv, x_proj_w, dt_w, dt_b, delta, Bsb, Csb);
  hipLaunchKernelGGL(k4_scan, dim3(384), dim3(64), 0, stream, xconv, delta, Bsb, Csb, A_logs, Ds, outy);
  hipLaunchKernelGGL(k5_combine_ln, dim3(4608), dim3(192), 0, stream, outy, onw, onb, yln);
  hipLaunchKernelGGL(k6a_xc, dim3(384), dim3(256), 0, stream, yln, xcb);
  hipLaunchKernelGGL(k6b_channel, dim3(1), dim3(256), 0, stream, xcb, cin_w, cin_b, cout_w, cout_b,
                     xc_proj_w, dtc_w, dtc_b, Ac_logs, Dsc, cn_w, cn_b, cvec);
  hipLaunchKernelGGL(k7_out, dim3(288), dim3(256), 0, stream, yln, cvec, zbuf, out_w, out_b, (float*)d_out);
}

// Round 2
// 440.475 us; speedup vs baseline: 2.9921x; 2.9921x over previous
//
#include <hip/hip_runtime.h>
#include <math.h>

#define DM 96
#define DE 192
#define LL 2304
#define NS 16
#define RK 6
#define NC 38   // RK + 2*NS
#define CH 16   // scan chunks
#define CLEN 144 // 2304/16

__device__ __forceinline__ float silu_f(float x){ return x / (1.f + __expf(-x)); }
__device__ __forceinline__ float softplus_f(float x){ return (x > 20.f) ? x : log1pf(__expf(x)); }

// xs[b,k,d,l] = xconv[b,d,dir_map(k,l)]
__device__ __forceinline__ int dir_map(int k, int l){
    switch(k){
      case 0: return l;
      case 1: return (l % 48) * 48 + l / 48;
      case 2: return 2303 - l;
      default: { int lr = 2303 - l; return (lr % 48) * 48 + lr / 48; }
    }
}

// K1: 1x1 conv in (96 -> 384), split into x1raw (first 192) and z=silu (last 192)
__global__ __launch_bounds__(384) void k1_conv_in(const float* __restrict__ x,
    const float* __restrict__ in_w, const float* __restrict__ in_b,
    float* __restrict__ x1raw, float* __restrict__ z){
  __shared__ float xv[DM*16];
  int tile = blockIdx.x;
  int b = tile / 144;
  int pos0 = (tile % 144) * 16;
  int tid = threadIdx.x;
  for (int i = tid; i < DM*16; i += 384){
    int c = i >> 4, p = i & 15;
    xv[c*16 + p] = x[(b*DM + c)*LL + pos0 + p];
  }
  __syncthreads();
  float acc[16];
  #pragma unroll
  for (int p=0;p<16;p++) acc[p] = in_b[tid];
  for (int c=0;c<DM;c++){
    float w = in_w[tid*DM + c];
    #pragma unroll
    for (int p=0;p<16;p++) acc[p] = fmaf(w, xv[c*16+p], acc[p]);
  }
  if (tid < DE){
    #pragma unroll
    for (int p=0;p<16;p++) x1raw[(b*DE + tid)*LL + pos0 + p] = acc[p];
  } else {
    int zc = tid - DE;
    #pragma unroll
    for (int p=0;p<16;p++) z[(b*DE + zc)*LL + pos0 + p] = silu_f(acc[p]);
  }
}

// K2: depthwise 3x3 SAME + bias + silu
__global__ __launch_bounds__(256) void k2_dwconv(const float* __restrict__ x1raw,
    const float* __restrict__ dw_w, const float* __restrict__ dw_b,
    float* __restrict__ xconv){
  int idx = blockIdx.x*256 + threadIdx.x;  // over B*DE*LL = 884736
  int pos = idx % LL; int bd = idx / LL;
  int d = bd % DE;
  int h = pos / 48, w = pos % 48;
  float acc = dw_b[d];
  #pragma unroll
  for (int kh=0;kh<3;kh++){
    int hh = h + kh - 1;
    if (hh < 0 || hh >= 48) continue;
    #pragma unroll
    for (int kw=0;kw<3;kw++){
      int ww_ = w + kw - 1;
      if (ww_ < 0 || ww_ >= 48) continue;
      acc = fmaf(dw_w[d*9 + kh*3 + kw], x1raw[bd*LL + hh*48 + ww_], acc);
    }
  }
  xconv[idx] = silu_f(acc);
}

// K3: x_dbl projection + dt projection + softplus; emit delta (b,k,d,l), Bs/Cs (b,k,l,16)
__global__ __launch_bounds__(64) void k3_proj(const float* __restrict__ xconv,
    const float* __restrict__ x_proj_w, const float* __restrict__ dt_w,
    const float* __restrict__ dt_b, float* __restrict__ delta,
    float* __restrict__ Bs, float* __restrict__ Cs){
  int bk = blockIdx.x / 36;
  int tile = blockIdx.x % 36;
  int b = bk >> 2, k = bk & 3;
  int l = tile*64 + threadIdx.x;
  float acc[NC];
  #pragma unroll
  for (int c=0;c<NC;c++) acc[c]=0.f;
  int pos = dir_map(k, l);
  const float* xc_base = xconv + b*DE*LL + pos;
  const float* wbase = x_proj_w + k*NC*DE;
  for (int d=0; d<DE; d++){
    float u = xc_base[d*LL];
    #pragma unroll
    for (int c=0;c<NC;c++) acc[c] = fmaf(u, wbase[c*DE + d], acc[c]);
  }
  const float* dwb = dt_w + k*DE*RK;
  const float* dbb = dt_b + k*DE;
  float* dout = delta + (bk*DE)*LL + l;
  for (int d=0; d<DE; d++){
    float t = dbb[d];
    #pragma unroll
    for (int r=0;r<RK;r++) t = fmaf(acc[r], dwb[d*RK + r], t);
    dout[d*LL] = softplus_f(t);
  }
  float* bptr = Bs + (bk*LL + l)*NS;
  float* cptr = Cs + (bk*LL + l)*NS;
  #pragma unroll
  for (int n=0;n<NS;n++){ bptr[n] = acc[RK+n]; cptr[n] = acc[RK+NS+n]; }
}

// K4: chunked selective scan. Block = one (b,k,d); lane = (chunk, n).
// Phase A: local chunk scan -> (P, S). Phase B: 16-step chunk-prefix combine in LDS.
// Phase C: rescan with correct h_in, write output in SPATIAL order.
__global__ __launch_bounds__(256) void k4_scan(const float* __restrict__ xconv,
    const float* __restrict__ delta, const float* __restrict__ Bs,
    const float* __restrict__ Cs, const float* __restrict__ A_logs,
    const float* __restrict__ Ds, float* __restrict__ out_y){
  int gid = blockIdx.x;           // [0, 1536) = b*4*DE + k*DE + d-ish
  int b = gid / (4*DE);
  int kd = gid % (4*DE);
  int k = kd / DE;
  int d = kd % DE;
  int bk = b*4 + k;
  int tid = threadIdx.x;
  int c = tid >> 4, n = tid & 15;
  float A  = -__expf(A_logs[(k*DE + d)*NS + n]);
  float Dv = Ds[k*DE + d];
  const float* dptr = delta + (bk*DE + d)*LL;
  const float* uptr = xconv + (b*DE + d)*LL;
  const float* bptr = Bs + bk*LL*NS + n;
  const float* cptr = Cs + bk*LL*NS + n;
  float* optr = out_y + (bk*DE + d)*LL;
  int l0 = c*CLEN;
  // Phase A
  float P = 1.f, S = 0.f;
  #pragma unroll 4
  for (int i=0;i<CLEN;i++){
    int l = l0 + i;
    float dl = dptr[l];
    float u  = uptr[dir_map(k, l)];
    float Bv = bptr[l*NS];
    float dA = __expf(dl * A);
    S = fmaf(S, dA, dl * u * Bv);
    P *= dA;
  }
  __shared__ float sP[CH][NS], sS[CH][NS];
  sP[c][n] = P; sS[c][n] = S;
  __syncthreads();
  // Phase B: lanes tid<16 each combine one n across chunks
  if (tid < NS){
    float hacc = 0.f;
    #pragma unroll
    for (int cc=0; cc<CH; cc++){
      hacc = fmaf(hacc, sP[cc][tid], sS[cc][tid]);
      sS[cc][tid] = hacc;   // inclusive prefix: h at END of chunk cc
    }
  }
  __syncthreads();
  float h = (c == 0) ? 0.f : sS[c-1][n];
  // Phase C
  #pragma unroll 4
  for (int i=0;i<CLEN;i++){
    int l = l0 + i;
    float dl = dptr[l];
    int pos = dir_map(k, l);
    float u  = uptr[pos];
    float Bv = bptr[l*NS];
    float Cv = cptr[l*NS];
    float dA = __expf(dl * A);
    h = fmaf(h, dA, dl * u * Bv);
    float py = h * Cv;
    py += __shfl_xor(py, 1);
    py += __shfl_xor(py, 2);
    py += __shfl_xor(py, 4);
    py += __shfl_xor(py, 8);
    if (n == 0) optr[pos] = fmaf(Dv, u, py);  // spatial order
  }
}

// K5: combine 4 directions (all stored in spatial order) + channel LayerNorm.
// Block: one b x 64-pixel tile; lanes over pixels, 4 channel-chunks of 48.
__global__ __launch_bounds__(256) void k5_combine_ln(const float* __restrict__ out_y,
    const float* __restrict__ onw, const float* __restrict__ onb,
    float* __restrict__ y_ln){
  __shared__ float vals[DE][64+1];   // ~50 KB
  __shared__ float s_[4][64], s2_[4][64];
  __shared__ float mu_[64], rs_[64];
  int bT = blockIdx.x;               // [0, 72)
  int b = bT / 36;
  int pos0 = (bT % 36) * 64;
  int tid = threadIdx.x;
  int p = tid & 63, dch = tid >> 6;
  const float* base = out_y + b*4*DE*LL;
  float s = 0.f, s2 = 0.f;
  for (int j=0;j<48;j++){
    int d = dch*48 + j;
    int idx = d*LL + pos0 + p;
    float v = base[idx] + base[DE*LL + idx] + base[2*DE*LL + idx] + base[3*DE*LL + idx];
    vals[d][p] = v;
    s += v; s2 += v*v;
  }
  s_[dch][p] = s; s2_[dch][p] = s2;
  __syncthreads();
  if (tid < 64){
    float ss  = s_[0][tid]+s_[1][tid]+s_[2][tid]+s_[3][tid];
    float ss2 = s2_[0][tid]+s2_[1][tid]+s2_[2][tid]+s2_[3][tid];
    float mu = ss / DE;
    float var = ss2 / DE - mu*mu;
    mu_[tid] = mu; rs_[tid] = rsqrtf(var + 1e-5f);
  }
  __syncthreads();
  float mu = mu_[p], rs = rs_[p];
  for (int j=0;j<48;j++){
    int d = dch*48 + j;
    y_ln[(b*DE + d)*LL + pos0 + p] = (vals[d][p] - mu)*rs*onw[d] + onb[d];
  }
}

// K6a: xc[b,d] = mean over pixels of y_ln
__global__ __launch_bounds__(256) void k6a_xc(const float* __restrict__ y_ln, float* __restrict__ xc){
  int row = blockIdx.x; // b*DE + d
  const float* p = y_ln + row*LL;
  float s = 0.f;
  for (int i = threadIdx.x; i < LL; i += 256) s += p[i];
  for (int off=32; off>0; off>>=1) s += __shfl_down(s, off);
  __shared__ float sw[4];
  int lane = threadIdx.x & 63, wid = threadIdx.x >> 6;
  if (lane==0) sw[wid] = s;
  __syncthreads();
  if (threadIdx.x==0) xc[row] = (sw[0]+sw[1]+sw[2]+sw[3]) * (1.f/LL);
}

// K6b: entire channel core in one block. wave = (b,k); lane -> (dc, n)
__global__ __launch_bounds__(256) void k6b_channel(const float* __restrict__ xc,
    const float* __restrict__ cin_w, const float* __restrict__ cin_b,
    const float* __restrict__ cout_w, const float* __restrict__ cout_b,
    const float* __restrict__ xc_proj_w, const float* __restrict__ dtc_w,
    const float* __restrict__ dtc_b, const float* __restrict__ Ac_logs,
    const float* __restrict__ Dsc, const float* __restrict__ cn_w,
    const float* __restrict__ cn_b, float* __restrict__ cvec){
  __shared__ float xcs[2][DE];
  __shared__ float outc[2][2][4][DE];
  __shared__ float ycs[2][DE];
  __shared__ float stats[2][2];
  int tid = threadIdx.x;
  for (int i = tid; i < 2*DE; i += 256) xcs[i/DE][i%DE] = xc[i];
  __syncthreads();
  int wv = tid >> 6;
  int b = wv >> 1, k = wv & 1;
  int lane = tid & 63;
  int dc = (lane >> 4) & 3, n = lane & 15;
  float EW[4], Bw[4], Cw[4];
  #pragma unroll
  for (int j=0;j<4;j++){
    float e = 0.f;
    #pragma unroll
    for (int r=0;r<RK;r++) e = fmaf(dtc_w[(k*4+dc)*RK + r], xc_proj_w[(k*NC + r)*4 + j], e);
    EW[j] = e;
    Bw[j] = xc_proj_w[(k*NC + RK + n)*4 + j];
    Cw[j] = xc_proj_w[(k*NC + RK + NS + n)*4 + j];
  }
  float A  = -__expf(Ac_logs[(k*4+dc)*NS + n]);
  float Dv = Dsc[k*4+dc];
  float dtb = dtc_b[k*4+dc];
  float ciw0=cin_w[0], ciw1=cin_w[1], ciw2=cin_w[2], ciw3=cin_w[3];
  float cib0=cin_b[0], cib1=cin_b[1], cib2=cin_b[2], cib3=cin_b[3];
  float h = 0.f;
  for (int lc=0; lc<DE; lc++){
    int lp = k ? (191 - lc) : lc;
    float xv = xcs[b][lp];
    float xs0 = fmaf(xv, ciw0, cib0);
    float xs1 = fmaf(xv, ciw1, cib1);
    float xs2 = fmaf(xv, ciw2, cib2);
    float xs3 = fmaf(xv, ciw3, cib3);
    float dt = dtb + xs0*EW[0] + xs1*EW[1] + xs2*EW[2] + xs3*EW[3];
    float dl = softplus_f(dt);
    float Bv = xs0*Bw[0] + xs1*Bw[1] + xs2*Bw[2] + xs3*Bw[3];
    float Cv = xs0*Cw[0] + xs1*Cw[1] + xs2*Cw[2] + xs3*Cw[3];
    float u = (dc==0)?xs0:((dc==1)?xs1:((dc==2)?xs2:xs3));
    float dA = __expf(dl * A);
    h = fmaf(h, dA, dl*u*Bv);
    float py = h * Cv;
    py += __shfl_xor(py, 1);
    py += __shfl_xor(py, 2);
    py += __shfl_xor(py, 4);
    py += __shfl_xor(py, 8);
    if (n==0) outc[b][k][dc][lc] = fmaf(Dv, u, py);
  }
  __syncthreads();
  float co0=cout_w[0], co1=cout_w[1], co2=cout_w[2], co3=cout_w[3], cob=cout_b[0];
  for (int i = tid; i < 2*DE; i += 256){
    int bb = i / DE, lc = i % DE;
    float yv = cob
      + co0*(outc[bb][0][0][lc] + outc[bb][1][0][191-lc])
      + co1*(outc[bb][0][1][lc] + outc[bb][1][1][191-lc])
      + co2*(outc[bb][0][2][lc] + outc[bb][1][2][191-lc])
      + co3*(outc[bb][0][3][lc] + outc[bb][1][3][191-lc]);
    ycs[bb][lc] = yv;
  }
  __syncthreads();
  if (tid < 2){
    float s=0.f, s2=0.f;
    for (int lc=0; lc<DE; lc++){ float v=ycs[tid][lc]; s+=v; s2+=v*v; }
    float mu = s/DE; float var = s2/DE - mu*mu;
    stats[tid][0]=mu; stats[tid][1]=rsqrtf(var+1e-5f);
  }
  __syncthreads();
  for (int i = tid; i < 2*DE; i += 256){
    int bb = i / DE, lc = i % DE;
    cvec[i] = (ycs[bb][lc] - stats[bb][0]) * stats[bb][1] * cn_w[lc] + cn_b[lc];
  }
}

// K7: out = conv1x1(y_ln * c * z), 192 -> 96
__global__ __launch_bounds__(256) void k7_out(const float* __restrict__ y_ln,
    const float* __restrict__ cvec, const float* __restrict__ z,
    const float* __restrict__ out_w, const float* __restrict__ out_b,
    float* __restrict__ outp){
  __shared__ float t[DE*16];
  int tile = blockIdx.x;
  int b = tile / 144;
  int pos0 = (tile % 144) * 16;
  int tid = threadIdx.x;
  for (int i = tid; i < DE*16; i += 256){
    int c = i >> 4, p = i & 15;
    int gi = (b*DE + c)*LL + pos0 + p;
    t[c*16 + p] = y_ln[gi] * cvec[b*DE + c] * z[gi];
  }
  __syncthreads();
  for (int j = tid; j < DM*16; j += 256){
    int o = j >> 4, p = j & 15;
    float acc = out_b[o];
    const float* wr = out_w + o*DE;
    #pragma unroll 4
    for (int c=0;c<DE;c++) acc = fmaf(wr[c], t[c*16+p], acc);
    outp[(b*DM + o)*LL + pos0 + p] = acc;
  }
}

extern "C" void kernel_launch(void* const* d_in, const int* in_sizes, int n_in,
                              void* d_out, int out_size, void* d_ws, size_t ws_size,
                              hipStream_t stream){
  const float* x        = (const float*)d_in[0];
  const float* in_w     = (const float*)d_in[1];
  const float* in_b     = (const float*)d_in[2];
  const float* dw_w     = (const float*)d_in[3];
  const float* dw_b     = (const float*)d_in[4];
  const float* x_proj_w = (const float*)d_in[5];
  const float* dt_w     = (const float*)d_in[6];
  const float* dt_b     = (const float*)d_in[7];
  const float* A_logs   = (const float*)d_in[8];
  const float* Ds       = (const float*)d_in[9];
  const float* onw      = (const float*)d_in[10];
  const float* onb      = (const float*)d_in[11];
  const float* cin_w    = (const float*)d_in[12];
  const float* cin_b    = (const float*)d_in[13];
  const float* cout_w   = (const float*)d_in[14];
  const float* cout_b   = (const float*)d_in[15];
  const float* xc_proj_w= (const float*)d_in[16];
  const float* dtc_w    = (const float*)d_in[17];
  const float* dtc_b    = (const float*)d_in[18];
  const float* Ac_logs  = (const float*)d_in[19];
  const float* Dsc      = (const float*)d_in[20];
  const float* cn_w     = (const float*)d_in[21];
  const float* cn_b     = (const float*)d_in[22];
  const float* out_w    = (const float*)d_in[23];
  const float* out_b    = (const float*)d_in[24];

  float* ws = (float*)d_ws;
  float* x1raw = ws;  ws += 2*DE*LL;
  float* zbuf  = ws;  ws += 2*DE*LL;
  float* xconv = ws;  ws += 2*DE*LL;
  float* delta = ws;  ws += 2*4*DE*LL;
  float* Bsb   = ws;  ws += 2*4*LL*NS;
  float* Csb   = ws;  ws += 2*4*LL*NS;
  float* outy  = ws;  ws += 2*4*DE*LL;
  float* yln   = ws;  ws += 2*DE*LL;
  float* xcb   = ws;  ws += 2*DE;
  float* cvec  = ws;  ws += 2*DE;

  hipLaunchKernelGGL(k1_conv_in, dim3(288), dim3(384), 0, stream, x, in_w, in_b, x1raw, zbuf);
  hipLaunchKernelGGL(k2_dwconv, dim3(3456), dim3(256), 0, stream, x1raw, dw_w, dw_b, xconv);
  hipLaunchKernelGGL(k3_proj, dim3(288), dim3(64), 0, stream, xconv, x_proj_w, dt_w, dt_b, delta, Bsb, Csb);
  hipLaunchKernelGGL(k4_scan, dim3(1536), dim3(256), 0, stream, xconv, delta, Bsb, Csb, A_logs, Ds, outy);
  hipLaunchKernelGGL(k5_combine_ln, dim3(72), dim3(256), 0, stream, outy, onw, onb, yln);
  hipLaunchKernelGGL(k6a_xc, dim3(384), dim3(256), 0, stream, yln, xcb);
  hipLaunchKernelGGL(k6b_channel, dim3(1), dim3(256), 0, stream, xcb, cin_w, cin_b, cout_w, cout_b,
                     xc_proj_w, dtc_w, dtc_b, Ac_logs, Dsc, cn_w, cn_b, cvec);
  hipLaunchKernelGGL(k7_out, dim3(288), dim3(256), 0, stream, yln, cvec, zbuf, out_w, out_b, (float*)d_out);
}

// Round 3
// 332.983 us; speedup vs baseline: 3.9580x; 1.3228x over previous
//
#include <hip/hip_runtime.h>
#include <math.h>

#define DM 96
#define DE 192
#define LL 2304
#define NS 16
#define RK 6
#define NC 38   // RK + 2*NS
#define CH 16   // scan chunks
#define CLEN 144 // 2304/16

__device__ __forceinline__ float silu_f(float x){ return x / (1.f + __expf(-x)); }
__device__ __forceinline__ float softplus_f(float x){ return (x > 20.f) ? x : log1pf(__expf(x)); }

// xs[b,k,d,l] = xconv[b,d,dir_map(k,l)]
__device__ __forceinline__ int dir_map(int k, int l){
    switch(k){
      case 0: return l;
      case 1: return (l % 48) * 48 + l / 48;
      case 2: return 2303 - l;
      default: { int lr = 2303 - l; return (lr % 48) * 48 + lr / 48; }
    }
}

// K1: 1x1 conv in (96 -> 384), split into x1raw (first 192) and z=silu (last 192)
__global__ __launch_bounds__(384) void k1_conv_in(const float* __restrict__ x,
    const float* __restrict__ in_w, const float* __restrict__ in_b,
    float* __restrict__ x1raw, float* __restrict__ z){
  __shared__ float xv[DM*16];
  int tile = blockIdx.x;
  int b = tile / 144;
  int pos0 = (tile % 144) * 16;
  int tid = threadIdx.x;
  for (int i = tid; i < DM*16; i += 384){
    int c = i >> 4, p = i & 15;
    xv[c*16 + p] = x[(b*DM + c)*LL + pos0 + p];
  }
  __syncthreads();
  float acc[16];
  #pragma unroll
  for (int p=0;p<16;p++) acc[p] = in_b[tid];
  for (int c=0;c<DM;c++){
    float w = in_w[tid*DM + c];
    #pragma unroll
    for (int p=0;p<16;p++) acc[p] = fmaf(w, xv[c*16+p], acc[p]);
  }
  if (tid < DE){
    #pragma unroll
    for (int p=0;p<16;p++) x1raw[(b*DE + tid)*LL + pos0 + p] = acc[p];
  } else {
    int zc = tid - DE;
    #pragma unroll
    for (int p=0;p<16;p++) z[(b*DE + zc)*LL + pos0 + p] = silu_f(acc[p]);
  }
}

// K2: depthwise 3x3 SAME + bias + silu
__global__ __launch_bounds__(256) void k2_dwconv(const float* __restrict__ x1raw,
    const float* __restrict__ dw_w, const float* __restrict__ dw_b,
    float* __restrict__ xconv){
  int idx = blockIdx.x*256 + threadIdx.x;  // over B*DE*LL = 884736
  int pos = idx % LL; int bd = idx / LL;
  int d = bd % DE;
  int h = pos / 48, w = pos % 48;
  float acc = dw_b[d];
  #pragma unroll
  for (int kh=0;kh<3;kh++){
    int hh = h + kh - 1;
    if (hh < 0 || hh >= 48) continue;
    #pragma unroll
    for (int kw=0;kw<3;kw++){
      int ww_ = w + kw - 1;
      if (ww_ < 0 || ww_ >= 48) continue;
      acc = fmaf(dw_w[d*9 + kh*3 + kw], x1raw[bd*LL + hh*48 + ww_], acc);
    }
  }
  xconv[idx] = silu_f(acc);
}

// K3 v2: d-split projection.
// Block = (bk, 64-l tile), 256 threads = 4 dgroups x 64 lanes.
// Phase 0: stage weights transposed [d][c_pad40] in LDS.
// Phase 1: each thread accumulates 38 c's over its 48 d's (u global, w LDS broadcast float4).
// Phase 2: LDS reduce over 4 dgroups; emit Bs/Cs; dt-projection + softplus -> delta.
__global__ __launch_bounds__(256) void k3_proj(const float* __restrict__ xconv,
    const float* __restrict__ x_proj_w, const float* __restrict__ dt_w,
    const float* __restrict__ dt_b, float* __restrict__ delta,
    float* __restrict__ Bs, float* __restrict__ Cs){
  __shared__ float smem[38*256];   // 38912 B; reused: weights (192*40) then partials (38*4*64)
  int bk = blockIdx.x / 36;
  int tile = blockIdx.x % 36;
  int b = bk >> 2, k = bk & 3;
  int tid = threadIdx.x;
  int lsub = tid & 63, dgrp = tid >> 6;
  int l = tile*64 + lsub;
  // Phase 0: weights -> LDS transposed, pad c to 40
  const float* wsrc = x_proj_w + k*NC*DE;
  for (int idx = tid; idx < NC*DE; idx += 256){
    int c = idx / DE, d = idx % DE;
    smem[d*40 + c] = wsrc[idx];
  }
  if (tid < DE){ smem[tid*40 + 38] = 0.f; smem[tid*40 + 39] = 0.f; }
  __syncthreads();
  // Phase 1
  float acc[40];
  #pragma unroll
  for (int c=0;c<40;c++) acc[c]=0.f;
  int pos = dir_map(k, l);
  const float* uptr = xconv + b*DE*LL + pos;
  for (int dd=0; dd<48; dd++){
    int d = dgrp*48 + dd;
    float u = uptr[d*LL];
    const float4* wrow = (const float4*)&smem[d*40];
    #pragma unroll
    for (int j=0;j<10;j++){
      float4 wv = wrow[j];
      acc[j*4+0] = fmaf(u, wv.x, acc[j*4+0]);
      acc[j*4+1] = fmaf(u, wv.y, acc[j*4+1]);
      acc[j*4+2] = fmaf(u, wv.z, acc[j*4+2]);
      acc[j*4+3] = fmaf(u, wv.w, acc[j*4+3]);
    }
  }
  __syncthreads();   // done reading weights
  // Phase 2a: write partials [c][dgrp][lsub]
  #pragma unroll
  for (int c=0;c<38;c++) smem[c*256 + dgrp*64 + lsub] = acc[c];
  __syncthreads();
  // Phase 2b: reduce over dgroups; keep dts rows in LDS; emit Bs/Cs
  for (int idx = tid; idx < 38*64; idx += 256){
    int c = idx >> 6, l2 = idx & 63;
    float s = smem[c*256 + l2] + smem[c*256 + 64 + l2]
            + smem[c*256 + 128 + l2] + smem[c*256 + 192 + l2];
    int lg = tile*64 + l2;
    if (c < RK){
      smem[c*256 + l2] = s;     // in-place: this thread owns this slot
    } else if (c < RK + NS){
      Bs[(bk*LL + lg)*NS + (c - RK)] = s;
    } else {
      Cs[(bk*LL + lg)*NS + (c - RK - NS)] = s;
    }
  }
  __syncthreads();
  // Phase 2c: dt projection + softplus, coalesced delta writes
  float r0 = smem[0*256 + lsub], r1 = smem[1*256 + lsub], r2 = smem[2*256 + lsub];
  float r3 = smem[3*256 + lsub], r4 = smem[4*256 + lsub], r5 = smem[5*256 + lsub];
  const float* dwb = dt_w + k*DE*RK;
  const float* dbb = dt_b + k*DE;
  for (int dd=0; dd<48; dd++){
    int d = dgrp*48 + dd;
    const float* wr = dwb + d*RK;
    float t = dbb[d];
    t = fmaf(r0, wr[0], t); t = fmaf(r1, wr[1], t); t = fmaf(r2, wr[2], t);
    t = fmaf(r3, wr[3], t); t = fmaf(r4, wr[4], t); t = fmaf(r5, wr[5], t);
    delta[(bk*DE + d)*LL + l] = softplus_f(t);
  }
}

// K4: chunked selective scan. Block = one (b,k,d); lane = (chunk, n).
__global__ __launch_bounds__(256) void k4_scan(const float* __restrict__ xconv,
    const float* __restrict__ delta, const float* __restrict__ Bs,
    const float* __restrict__ Cs, const float* __restrict__ A_logs,
    const float* __restrict__ Ds, float* __restrict__ out_y){
  int gid = blockIdx.x;           // [0, 1536)
  int b = gid / (4*DE);
  int kd = gid % (4*DE);
  int k = kd / DE;
  int d = kd % DE;
  int bk = b*4 + k;
  int tid = threadIdx.x;
  int c = tid >> 4, n = tid & 15;
  float A  = -__expf(A_logs[(k*DE + d)*NS + n]);
  float Dv = Ds[k*DE + d];
  const float* dptr = delta + (bk*DE + d)*LL;
  const float* uptr = xconv + (b*DE + d)*LL;
  const float* bptr = Bs + bk*LL*NS + n;
  const float* cptr = Cs + bk*LL*NS + n;
  float* optr = out_y + (bk*DE + d)*LL;
  int l0 = c*CLEN;
  // Phase A
  float P = 1.f, S = 0.f;
  #pragma unroll 4
  for (int i=0;i<CLEN;i++){
    int l = l0 + i;
    float dl = dptr[l];
    float u  = uptr[dir_map(k, l)];
    float Bv = bptr[l*NS];
    float dA = __expf(dl * A);
    S = fmaf(S, dA, dl * u * Bv);
    P *= dA;
  }
  __shared__ float sP[CH][NS], sS[CH][NS];
  sP[c][n] = P; sS[c][n] = S;
  __syncthreads();
  if (tid < NS){
    float hacc = 0.f;
    #pragma unroll
    for (int cc=0; cc<CH; cc++){
      hacc = fmaf(hacc, sP[cc][tid], sS[cc][tid]);
      sS[cc][tid] = hacc;
    }
  }
  __syncthreads();
  float h = (c == 0) ? 0.f : sS[c-1][n];
  // Phase C
  #pragma unroll 4
  for (int i=0;i<CLEN;i++){
    int l = l0 + i;
    float dl = dptr[l];
    int pos = dir_map(k, l);
    float u  = uptr[pos];
    float Bv = bptr[l*NS];
    float Cv = cptr[l*NS];
    float dA = __expf(dl * A);
    h = fmaf(h, dA, dl * u * Bv);
    float py = h * Cv;
    py += __shfl_xor(py, 1);
    py += __shfl_xor(py, 2);
    py += __shfl_xor(py, 4);
    py += __shfl_xor(py, 8);
    if (n == 0) optr[pos] = fmaf(Dv, u, py);  // spatial order
  }
}

// K5 v2: combine 4 directions + channel LayerNorm. 16-pixel tiles, 288 blocks.
__global__ __launch_bounds__(256) void k5_combine_ln(const float* __restrict__ out_y,
    const float* __restrict__ onw, const float* __restrict__ onb,
    float* __restrict__ y_ln){
  __shared__ float vals[DE][17];
  __shared__ float s_[16][16], s2_[16][16];
  __shared__ float mu_[16], rs_[16];
  int bT = blockIdx.x;               // [0, 288)
  int b = bT / 144;
  int pos0 = (bT % 144) * 16;
  int tid = threadIdx.x;
  int p = tid & 15, g = tid >> 4;
  const float* base = out_y + b*4*DE*LL;
  float s = 0.f, s2 = 0.f;
  #pragma unroll
  for (int j=0;j<12;j++){
    int d = g*12 + j;
    int idx = d*LL + pos0 + p;
    float v = base[idx] + base[DE*LL + idx] + base[2*DE*LL + idx] + base[3*DE*LL + idx];
    vals[d][p] = v;
    s += v; s2 += v*v;
  }
  s_[g][p] = s; s2_[g][p] = s2;
  __syncthreads();
  if (tid < 16){
    float ss = 0.f, ss2 = 0.f;
    #pragma unroll
    for (int gg=0; gg<16; gg++){ ss += s_[gg][tid]; ss2 += s2_[gg][tid]; }
    float mu = ss / DE;
    float var = ss2 / DE - mu*mu;
    mu_[tid] = mu; rs_[tid] = rsqrtf(var + 1e-5f);
  }
  __syncthreads();
  float mu = mu_[p], rs = rs_[p];
  #pragma unroll
  for (int j=0;j<12;j++){
    int d = g*12 + j;
    y_ln[(b*DE + d)*LL + pos0 + p] = (vals[d][p] - mu)*rs*onw[d] + onb[d];
  }
}

// K6a: xc[b,d] = mean over pixels of y_ln
__global__ __launch_bounds__(256) void k6a_xc(const float* __restrict__ y_ln, float* __restrict__ xc){
  int row = blockIdx.x; // b*DE + d
  const float* p = y_ln + row*LL;
  float s = 0.f;
  for (int i = threadIdx.x; i < LL; i += 256) s += p[i];
  for (int off=32; off>0; off>>=1) s += __shfl_down(s, off);
  __shared__ float sw[4];
  int lane = threadIdx.x & 63, wid = threadIdx.x >> 6;
  if (lane==0) sw[wid] = s;
  __syncthreads();
  if (threadIdx.x==0) xc[row] = (sw[0]+sw[1]+sw[2]+sw[3]) * (1.f/LL);
}

// K6b: entire channel core in one block. wave = (b,k); lane -> (dc, n)
__global__ __launch_bounds__(256) void k6b_channel(const float* __restrict__ xc,
    const float* __restrict__ cin_w, const float* __restrict__ cin_b,
    const float* __restrict__ cout_w, const float* __restrict__ cout_b,
    const float* __restrict__ xc_proj_w, const float* __restrict__ dtc_w,
    const float* __restrict__ dtc_b, const float* __restrict__ Ac_logs,
    const float* __restrict__ Dsc, const float* __restrict__ cn_w,
    const float* __restrict__ cn_b, float* __restrict__ cvec){
  __shared__ float xcs[2][DE];
  __shared__ float outc[2][2][4][DE];
  __shared__ float ycs[2][DE];
  __shared__ float stats[2][2];
  int tid = threadIdx.x;
  for (int i = tid; i < 2*DE; i += 256) xcs[i/DE][i%DE] = xc[i];
  __syncthreads();
  int wv = tid >> 6;
  int b = wv >> 1, k = wv & 1;
  int lane = tid & 63;
  int dc = (lane >> 4) & 3, n = lane & 15;
  float EW[4], Bw[4], Cw[4];
  #pragma unroll
  for (int j=0;j<4;j++){
    float e = 0.f;
    #pragma unroll
    for (int r=0;r<RK;r++) e = fmaf(dtc_w[(k*4+dc)*RK + r], xc_proj_w[(k*NC + r)*4 + j], e);
    EW[j] = e;
    Bw[j] = xc_proj_w[(k*NC + RK + n)*4 + j];
    Cw[j] = xc_proj_w[(k*NC + RK + NS + n)*4 + j];
  }
  float A  = -__expf(Ac_logs[(k*4+dc)*NS + n]);
  float Dv = Dsc[k*4+dc];
  float dtb = dtc_b[k*4+dc];
  float ciw0=cin_w[0], ciw1=cin_w[1], ciw2=cin_w[2], ciw3=cin_w[3];
  float cib0=cin_b[0], cib1=cin_b[1], cib2=cin_b[2], cib3=cin_b[3];
  float h = 0.f;
  for (int lc=0; lc<DE; lc++){
    int lp = k ? (191 - lc) : lc;
    float xv = xcs[b][lp];
    float xs0 = fmaf(xv, ciw0, cib0);
    float xs1 = fmaf(xv, ciw1, cib1);
    float xs2 = fmaf(xv, ciw2, cib2);
    float xs3 = fmaf(xv, ciw3, cib3);
    float dt = dtb + xs0*EW[0] + xs1*EW[1] + xs2*EW[2] + xs3*EW[3];
    float dl = softplus_f(dt);
    float Bv = xs0*Bw[0] + xs1*Bw[1] + xs2*Bw[2] + xs3*Bw[3];
    float Cv = xs0*Cw[0] + xs1*Cw[1] + xs2*Cw[2] + xs3*Cw[3];
    float u = (dc==0)?xs0:((dc==1)?xs1:((dc==2)?xs2:xs3));
    float dA = __expf(dl * A);
    h = fmaf(h, dA, dl*u*Bv);
    float py = h * Cv;
    py += __shfl_xor(py, 1);
    py += __shfl_xor(py, 2);
    py += __shfl_xor(py, 4);
    py += __shfl_xor(py, 8);
    if (n==0) outc[b][k][dc][lc] = fmaf(Dv, u, py);
  }
  __syncthreads();
  float co0=cout_w[0], co1=cout_w[1], co2=cout_w[2], co3=cout_w[3], cob=cout_b[0];
  for (int i = tid; i < 2*DE; i += 256){
    int bb = i / DE, lc = i % DE;
    float yv = cob
      + co0*(outc[bb][0][0][lc] + outc[bb][1][0][191-lc])
      + co1*(outc[bb][0][1][lc] + outc[bb][1][1][191-lc])
      + co2*(outc[bb][0][2][lc] + outc[bb][1][2][191-lc])
      + co3*(outc[bb][0][3][lc] + outc[bb][1][3][191-lc]);
    ycs[bb][lc] = yv;
  }
  __syncthreads();
  if (tid < 2){
    float s=0.f, s2=0.f;
    for (int lc=0; lc<DE; lc++){ float v=ycs[tid][lc]; s+=v; s2+=v*v; }
    float mu = s/DE; float var = s2/DE - mu*mu;
    stats[tid][0]=mu; stats[tid][1]=rsqrtf(var+1e-5f);
  }
  __syncthreads();
  for (int i = tid; i < 2*DE; i += 256){
    int bb = i / DE, lc = i % DE;
    cvec[i] = (ycs[bb][lc] - stats[bb][0]) * stats[bb][1] * cn_w[lc] + cn_b[lc];
  }
}

// K7: out = conv1x1(y_ln * c * z), 192 -> 96
__global__ __launch_bounds__(256) void k7_out(const float* __restrict__ y_ln,
    const float* __restrict__ cvec, const float* __restrict__ z,
    const float* __restrict__ out_w, const float* __restrict__ out_b,
    float* __restrict__ outp){
  __shared__ float t[DE*16];
  int tile = blockIdx.x;
  int b = tile / 144;
  int pos0 = (tile % 144) * 16;
  int tid = threadIdx.x;
  for (int i = tid; i < DE*16; i += 256){
    int c = i >> 4, p = i & 15;
    int gi = (b*DE + c)*LL + pos0 + p;
    t[c*16 + p] = y_ln[gi] * cvec[b*DE + c] * z[gi];
  }
  __syncthreads();
  for (int j = tid; j < DM*16; j += 256){
    int o = j >> 4, p = j & 15;
    float acc = out_b[o];
    const float* wr = out_w + o*DE;
    #pragma unroll 4
    for (int c=0;c<DE;c++) acc = fmaf(wr[c], t[c*16+p], acc);
    outp[(b*DM + o)*LL + pos0 + p] = acc;
  }
}

extern "C" void kernel_launch(void* const* d_in, const int* in_sizes, int n_in,
                              void* d_out, int out_size, void* d_ws, size_t ws_size,
                              hipStream_t stream){
  const float* x        = (const float*)d_in[0];
  const float* in_w     = (const float*)d_in[1];
  const float* in_b     = (const float*)d_in[2];
  const float* dw_w     = (const float*)d_in[3];
  const float* dw_b     = (const float*)d_in[4];
  const float* x_proj_w = (const float*)d_in[5];
  const float* dt_w     = (const float*)d_in[6];
  const float* dt_b     = (const float*)d_in[7];
  const float* A_logs   = (const float*)d_in[8];
  const float* Ds       = (const float*)d_in[9];
  const float* onw      = (const float*)d_in[10];
  const float* onb      = (const float*)d_in[11];
  const float* cin_w    = (const float*)d_in[12];
  const float* cin_b    = (const float*)d_in[13];
  const float* cout_w   = (const float*)d_in[14];
  const float* cout_b   = (const float*)d_in[15];
  const float* xc_proj_w= (const float*)d_in[16];
  const float* dtc_w    = (const float*)d_in[17];
  const float* dtc_b    = (const float*)d_in[18];
  const float* Ac_logs  = (const float*)d_in[19];
  const float* Dsc      = (const float*)d_in[20];
  const float* cn_w     = (const float*)d_in[21];
  const float* cn_b     = (const float*)d_in[22];
  const float* out_w    = (const float*)d_in[23];
  const float* out_b    = (const float*)d_in[24];

  float* ws = (float*)d_ws;
  float* x1raw = ws;  ws += 2*DE*LL;
  float* zbuf  = ws;  ws += 2*DE*LL;
  float* xconv = ws;  ws += 2*DE*LL;
  float* delta = ws;  ws += 2*4*DE*LL;
  float* Bsb   = ws;  ws += 2*4*LL*NS;
  float* Csb   = ws;  ws += 2*4*LL*NS;
  float* outy  = ws;  ws += 2*4*DE*LL;
  float* yln   = ws;  ws += 2*DE*LL;
  float* xcb   = ws;  ws += 2*DE;
  float* cvec  = ws;  ws += 2*DE;

  hipLaunchKernelGGL(k1_conv_in, dim3(288), dim3(384), 0, stream, x, in_w, in_b, x1raw, zbuf);
  hipLaunchKernelGGL(k2_dwconv, dim3(3456), dim3(256), 0, stream, x1raw, dw_w, dw_b, xconv);
  hipLaunchKernelGGL(k3_proj, dim3(288), dim3(256), 0, stream, xconv, x_proj_w, dt_w, dt_b, delta, Bsb, Csb);
  hipLaunchKernelGGL(k4_scan, dim3(1536), dim3(256), 0, stream, xconv, delta, Bsb, Csb, A_logs, Ds, outy);
  hipLaunchKernelGGL(k5_combine_ln, dim3(288), dim3(256), 0, stream, outy, onw, onb, yln);
  hipLaunchKernelGGL(k6a_xc, dim3(384), dim3(256), 0, stream, yln, xcb);
  hipLaunchKernelGGL(k6b_channel, dim3(1), dim3(256), 0, stream, xcb, cin_w, cin_b, cout_w, cout_b,
                     xc_proj_w, dtc_w, dtc_b, Ac_logs, Dsc, cn_w, cn_b, cvec);
  hipLaunchKernelGGL(k7_out, dim3(288), dim3(256), 0, stream, yln, cvec, zbuf, out_w, out_b, (float*)d_out);
}

// Round 4
// 310.599 us; speedup vs baseline: 4.2433x; 1.0721x over previous
//
#include <hip/hip_runtime.h>
#include <math.h>

#define DM 96
#define DE 192
#define LL 2304
#define NS 16
#define RK 6
#define NC 38   // RK + 2*NS
#define CH4 64  // scan chunks (k4 v3)
#define CL4 36  // 2304/64

__device__ __forceinline__ float silu_f(float x){ return x / (1.f + __expf(-x)); }
__device__ __forceinline__ float softplus_f(float x){ return (x > 20.f) ? x : log1pf(__expf(x)); }

// xs[b,k,d,l] = xconv[b,d,dir_map(k,l)]
__device__ __forceinline__ int dir_map(int k, int l){
    switch(k){
      case 0: return l;
      case 1: return (l % 48) * 48 + l / 48;
      case 2: return 2303 - l;
      default: { int lr = 2303 - l; return (lr % 48) * 48 + lr / 48; }
    }
}

// K1: 1x1 conv in (96 -> 384), split into x1raw (first 192) and z=silu (last 192)
__global__ __launch_bounds__(384) void k1_conv_in(const float* __restrict__ x,
    const float* __restrict__ in_w, const float* __restrict__ in_b,
    float* __restrict__ x1raw, float* __restrict__ z){
  __shared__ float xv[DM*16];
  int tile = blockIdx.x;
  int b = tile / 144;
  int pos0 = (tile % 144) * 16;
  int tid = threadIdx.x;
  for (int i = tid; i < DM*16; i += 384){
    int c = i >> 4, p = i & 15;
    xv[c*16 + p] = x[(b*DM + c)*LL + pos0 + p];
  }
  __syncthreads();
  float acc[16];
  #pragma unroll
  for (int p=0;p<16;p++) acc[p] = in_b[tid];
  for (int c=0;c<DM;c++){
    float w = in_w[tid*DM + c];
    #pragma unroll
    for (int p=0;p<16;p++) acc[p] = fmaf(w, xv[c*16+p], acc[p]);
  }
  if (tid < DE){
    #pragma unroll
    for (int p=0;p<16;p++) x1raw[(b*DE + tid)*LL + pos0 + p] = acc[p];
  } else {
    int zc = tid - DE;
    #pragma unroll
    for (int p=0;p<16;p++) z[(b*DE + zc)*LL + pos0 + p] = silu_f(acc[p]);
  }
}

// K2 v2: depthwise 3x3 + silu via LDS plane; emits xconv AND xconvT (transposed).
// Block = one (b,d) 48x48 plane.
__global__ __launch_bounds__(256) void k2_dwconv(const float* __restrict__ x1raw,
    const float* __restrict__ dw_w, const float* __restrict__ dw_b,
    float* __restrict__ xconv, float* __restrict__ xconvT){
  __shared__ float lin[50][52];
  __shared__ float lout[48][50];
  int bd = blockIdx.x;        // b*DE + d
  int d = bd % DE;
  int tid = threadIdx.x;
  for (int i = tid; i < 50*52; i += 256) ((float*)lin)[i] = 0.f;
  __syncthreads();
  const float* src = x1raw + bd*LL;
  for (int i = tid; i < LL; i += 256){
    lin[i/48 + 1][i%48 + 1] = src[i];
  }
  float w00=dw_w[d*9+0], w01=dw_w[d*9+1], w02=dw_w[d*9+2];
  float w10=dw_w[d*9+3], w11=dw_w[d*9+4], w12=dw_w[d*9+5];
  float w20=dw_w[d*9+6], w21=dw_w[d*9+7], w22=dw_w[d*9+8];
  float bias = dw_b[d];
  __syncthreads();
  float* dst = xconv + bd*LL;
  for (int i = tid; i < LL; i += 256){
    int h = i/48, w = i%48;
    float acc = bias;
    acc = fmaf(w00, lin[h  ][w], fmaf(w01, lin[h  ][w+1], fmaf(w02, lin[h  ][w+2], acc)));
    acc = fmaf(w10, lin[h+1][w], fmaf(w11, lin[h+1][w+1], fmaf(w12, lin[h+1][w+2], acc)));
    acc = fmaf(w20, lin[h+2][w], fmaf(w21, lin[h+2][w+1], fmaf(w22, lin[h+2][w+2], acc)));
    float v = silu_f(acc);
    dst[i] = v;
    lout[h][w] = v;
  }
  __syncthreads();
  float* dstT = xconvT + bd*LL;
  for (int i = tid; i < LL; i += 256){
    int tw = i/48, th = i%48;   // T[w*48+h] = X[h*48+w]
    dstT[i] = lout[th][tw];
  }
}

// K3: d-split projection (uses xconvT for coalesced odd-k reads).
__global__ __launch_bounds__(256) void k3_proj(const float* __restrict__ xconv,
    const float* __restrict__ xconvT,
    const float* __restrict__ x_proj_w, const float* __restrict__ dt_w,
    const float* __restrict__ dt_b, float* __restrict__ delta,
    float* __restrict__ Bs, float* __restrict__ Cs){
  __shared__ float smem[38*256];
  int bk = blockIdx.x / 36;
  int tile = blockIdx.x % 36;
  int b = bk >> 2, k = bk & 3;
  int tid = threadIdx.x;
  int lsub = tid & 63, dgrp = tid >> 6;
  int l = tile*64 + lsub;
  const float* wsrc = x_proj_w + k*NC*DE;
  for (int idx = tid; idx < NC*DE; idx += 256){
    int c = idx / DE, d = idx % DE;
    smem[d*40 + c] = wsrc[idx];
  }
  if (tid < DE){ smem[tid*40 + 38] = 0.f; smem[tid*40 + 39] = 0.f; }
  __syncthreads();
  float acc[40];
  #pragma unroll
  for (int c=0;c<40;c++) acc[c]=0.f;
  const float* uptr;
  {
    const float* basep = (k & 1) ? (xconvT + b*DE*LL) : (xconv + b*DE*LL);
    uptr = basep + ((k >= 2) ? (2303 - l) : l);
  }
  for (int dd=0; dd<48; dd++){
    int d = dgrp*48 + dd;
    float u = uptr[d*LL];
    const float4* wrow = (const float4*)&smem[d*40];
    #pragma unroll
    for (int j=0;j<10;j++){
      float4 wv = wrow[j];
      acc[j*4+0] = fmaf(u, wv.x, acc[j*4+0]);
      acc[j*4+1] = fmaf(u, wv.y, acc[j*4+1]);
      acc[j*4+2] = fmaf(u, wv.z, acc[j*4+2]);
      acc[j*4+3] = fmaf(u, wv.w, acc[j*4+3]);
    }
  }
  __syncthreads();
  #pragma unroll
  for (int c=0;c<38;c++) smem[c*256 + dgrp*64 + lsub] = acc[c];
  __syncthreads();
  for (int idx = tid; idx < 38*64; idx += 256){
    int c = idx >> 6, l2 = idx & 63;
    float s = smem[c*256 + l2] + smem[c*256 + 64 + l2]
            + smem[c*256 + 128 + l2] + smem[c*256 + 192 + l2];
    int lg = tile*64 + l2;
    if (c < RK){
      smem[c*256 + l2] = s;
    } else if (c < RK + NS){
      Bs[(bk*LL + lg)*NS + (c - RK)] = s;
    } else {
      Cs[(bk*LL + lg)*NS + (c - RK - NS)] = s;
    }
  }
  __syncthreads();
  float r0 = smem[0*256 + lsub], r1 = smem[1*256 + lsub], r2 = smem[2*256 + lsub];
  float r3 = smem[3*256 + lsub], r4 = smem[4*256 + lsub], r5 = smem[5*256 + lsub];
  const float* dwb = dt_w + k*DE*RK;
  const float* dbb = dt_b + k*DE;
  for (int dd=0; dd<48; dd++){
    int d = dgrp*48 + dd;
    const float* wr = dwb + d*RK;
    float t = dbb[d];
    t = fmaf(r0, wr[0], t); t = fmaf(r1, wr[1], t); t = fmaf(r2, wr[2], t);
    t = fmaf(r3, wr[3], t); t = fmaf(r4, wr[4], t); t = fmaf(r5, wr[5], t);
    delta[(bk*DE + d)*LL + l] = softplus_f(t);
  }
}

// K4 v3: chunked scan, lane = (chunk c of 64, n-quad q of 4), all float4 loads.
__global__ __launch_bounds__(256) void k4_scan(const float* __restrict__ xconv,
    const float* __restrict__ xconvT,
    const float* __restrict__ delta, const float* __restrict__ Bs,
    const float* __restrict__ Cs, const float* __restrict__ A_logs,
    const float* __restrict__ Ds, float* __restrict__ out_y){
  int gid = blockIdx.x;           // [0, 1536)
  int b = gid / (4*DE);
  int kd = gid % (4*DE);
  int k = kd / DE;
  int d = kd % DE;
  int bk = b*4 + k;
  int tid = threadIdx.x;
  int c = tid >> 2, q = tid & 3;
  const float LOG2E = 1.44269504f;
  float4 al = *(const float4*)&A_logs[(k*DE + d)*NS + q*4];
  float A2[4];
  A2[0] = -__expf(al.x)*LOG2E; A2[1] = -__expf(al.y)*LOG2E;
  A2[2] = -__expf(al.z)*LOG2E; A2[3] = -__expf(al.w)*LOG2E;
  float Dv = Ds[k*DE + d];
  const float* dptr = delta + (bk*DE + d)*LL;
  const float* ub = ((k & 1) ? xconvT : xconv) + (b*DE + d)*LL;
  bool rev = (k >= 2);
  const float* bbase = Bs + bk*LL*NS + q*4;
  const float* cbase = Cs + bk*LL*NS + q*4;
  float* optr = out_y + (bk*DE + d)*LL;
  int l0 = c*CL4;
  // Phase A: local (P, S) per chunk
  float P[4] = {1.f,1.f,1.f,1.f}, S[4] = {0.f,0.f,0.f,0.f};
  for (int i=0;i<CL4;i+=4){
    int l = l0 + i;
    float4 dl4 = *(const float4*)(dptr + l);
    float4 u4;
    if (!rev) u4 = *(const float4*)(ub + l);
    else { float4 t = *(const float4*)(ub + (LL-4) - l); u4 = make_float4(t.w,t.z,t.y,t.x); }
    #pragma unroll
    for (int j=0;j<4;j++){
      float dlj = (j==0)?dl4.x:((j==1)?dl4.y:((j==2)?dl4.z:dl4.w));
      float uj  = (j==0)?u4.x:((j==1)?u4.y:((j==2)?u4.z:u4.w));
      float du = dlj*uj;
      float4 Bv = *(const float4*)(bbase + (l+j)*NS);
      float dA0 = exp2f(dlj*A2[0]); S[0] = fmaf(S[0], dA0, du*Bv.x); P[0]*=dA0;
      float dA1 = exp2f(dlj*A2[1]); S[1] = fmaf(S[1], dA1, du*Bv.y); P[1]*=dA1;
      float dA2 = exp2f(dlj*A2[2]); S[2] = fmaf(S[2], dA2, du*Bv.z); P[2]*=dA2;
      float dA3 = exp2f(dlj*A2[3]); S[3] = fmaf(S[3], dA3, du*Bv.w); P[3]*=dA3;
    }
  }
  __shared__ float sP[CH4][NS], sS[CH4][NS];
  *(float4*)&sP[c][q*4] = make_float4(P[0],P[1],P[2],P[3]);
  *(float4*)&sS[c][q*4] = make_float4(S[0],S[1],S[2],S[3]);
  __syncthreads();
  // Phase B: 16 threads, serial combine over 64 chunks
  if (tid < NS){
    float hacc = 0.f;
    #pragma unroll 4
    for (int cc=0; cc<CH4; cc++){
      hacc = fmaf(hacc, sP[cc][tid], sS[cc][tid]);
      sS[cc][tid] = hacc;
    }
  }
  __syncthreads();
  float h[4];
  if (c == 0){ h[0]=h[1]=h[2]=h[3]=0.f; }
  else { float4 hi = *(const float4*)&sS[c-1][q*4]; h[0]=hi.x; h[1]=hi.y; h[2]=hi.z; h[3]=hi.w; }
  // Phase C: rescan + output (spatial order)
  for (int i=0;i<CL4;i+=4){
    int l = l0 + i;
    float4 dl4 = *(const float4*)(dptr + l);
    float4 u4;
    if (!rev) u4 = *(const float4*)(ub + l);
    else { float4 t = *(const float4*)(ub + (LL-4) - l); u4 = make_float4(t.w,t.z,t.y,t.w==t.w?t.x:t.x); }
    #pragma unroll
    for (int j=0;j<4;j++){
      float dlj = (j==0)?dl4.x:((j==1)?dl4.y:((j==2)?dl4.z:dl4.w));
      float uj  = (j==0)?u4.x:((j==1)?u4.y:((j==2)?u4.z:u4.w));
      float du = dlj*uj;
      float4 Bv = *(const float4*)(bbase + (l+j)*NS);
      float4 Cv = *(const float4*)(cbase + (l+j)*NS);
      float dA0 = exp2f(dlj*A2[0]); h[0] = fmaf(h[0], dA0, du*Bv.x);
      float dA1 = exp2f(dlj*A2[1]); h[1] = fmaf(h[1], dA1, du*Bv.y);
      float dA2 = exp2f(dlj*A2[2]); h[2] = fmaf(h[2], dA2, du*Bv.z);
      float dA3 = exp2f(dlj*A2[3]); h[3] = fmaf(h[3], dA3, du*Bv.w);
      float py = h[0]*Cv.x + h[1]*Cv.y + h[2]*Cv.z + h[3]*Cv.w;
      py += __shfl_xor(py, 1);
      py += __shfl_xor(py, 2);
      if (q == 0){
        int pos = dir_map(k, l+j);
        optr[pos] = fmaf(Dv, uj, py);
      }
    }
  }
}

// K5: combine 4 dirs + channel LN; also emit per-tile channel partial sums.
__global__ __launch_bounds__(256) void k5_combine_ln(const float* __restrict__ out_y,
    const float* __restrict__ onw, const float* __restrict__ onb,
    float* __restrict__ y_ln, float* __restrict__ partial){
  __shared__ float vals[DE][17];
  __shared__ float s_[16][16], s2_[16][16];
  __shared__ float mu_[16], rs_[16];
  int bT = blockIdx.x;               // [0, 288) = b*144 + tile
  int b = bT / 144;
  int pos0 = (bT % 144) * 16;
  int tid = threadIdx.x;
  int p = tid & 15, g = tid >> 4;
  const float* base = out_y + b*4*DE*LL;
  float s = 0.f, s2 = 0.f;
  #pragma unroll
  for (int j=0;j<12;j++){
    int d = g*12 + j;
    int idx = d*LL + pos0 + p;
    float v = base[idx] + base[DE*LL + idx] + base[2*DE*LL + idx] + base[3*DE*LL + idx];
    vals[d][p] = v;
    s += v; s2 += v*v;
  }
  s_[g][p] = s; s2_[g][p] = s2;
  __syncthreads();
  if (tid < 16){
    float ss = 0.f, ss2 = 0.f;
    #pragma unroll
    for (int gg=0; gg<16; gg++){ ss += s_[gg][tid]; ss2 += s2_[gg][tid]; }
    float mu = ss / DE;
    float var = ss2 / DE - mu*mu;
    mu_[tid] = mu; rs_[tid] = rsqrtf(var + 1e-5f);
  }
  __syncthreads();
  float mu = mu_[p], rs = rs_[p];
  #pragma unroll
  for (int j=0;j<12;j++){
    int d = g*12 + j;
    float yv = (vals[d][p] - mu)*rs*onw[d] + onb[d];
    y_ln[(b*DE + d)*LL + pos0 + p] = yv;
    vals[d][p] = yv;
  }
  __syncthreads();
  if (tid < DE){
    float ps = 0.f;
    #pragma unroll
    for (int pp=0;pp<16;pp++) ps += vals[tid][pp];
    partial[bT*DE + tid] = ps;
  }
}

// K6b v2: channel core; absorbs xc reduction from partials. One block.
__global__ __launch_bounds__(256) void k6b_channel(const float* __restrict__ partial,
    const float* __restrict__ cin_w, const float* __restrict__ cin_b,
    const float* __restrict__ cout_w, const float* __restrict__ cout_b,
    const float* __restrict__ xc_proj_w, const float* __restrict__ dtc_w,
    const float* __restrict__ dtc_b, const float* __restrict__ Ac_logs,
    const float* __restrict__ Dsc, const float* __restrict__ cn_w,
    const float* __restrict__ cn_b, float* __restrict__ cvec){
  __shared__ float xcs[2][DE];
  __shared__ float outc[2][2][4][DE];
  __shared__ float ycs[2][DE];
  __shared__ float stats[2][2];
  int tid = threadIdx.x;
  for (int r = tid; r < 2*DE; r += 256){
    int bb = r / DE, dd = r % DE;
    const float* pp = partial + bb*144*DE + dd;
    float sacc = 0.f;
    #pragma unroll 4
    for (int t=0;t<144;t++) sacc += pp[t*DE];
    xcs[bb][dd] = sacc * (1.f/LL);
  }
  __syncthreads();
  int wv = tid >> 6;
  int b = wv >> 1, k = wv & 1;
  int lane = tid & 63;
  int dc = (lane >> 4) & 3, n = lane & 15;
  float EW[4], Bw[4], Cw[4];
  #pragma unroll
  for (int j=0;j<4;j++){
    float e = 0.f;
    #pragma unroll
    for (int r=0;r<RK;r++) e = fmaf(dtc_w[(k*4+dc)*RK + r], xc_proj_w[(k*NC + r)*4 + j], e);
    EW[j] = e;
    Bw[j] = xc_proj_w[(k*NC + RK + n)*4 + j];
    Cw[j] = xc_proj_w[(k*NC + RK + NS + n)*4 + j];
  }
  float A  = -__expf(Ac_logs[(k*4+dc)*NS + n]);
  float Dv = Dsc[k*4+dc];
  float dtb = dtc_b[k*4+dc];
  float ciw0=cin_w[0], ciw1=cin_w[1], ciw2=cin_w[2], ciw3=cin_w[3];
  float cib0=cin_b[0], cib1=cin_b[1], cib2=cin_b[2], cib3=cin_b[3];
  float h = 0.f;
  for (int lc=0; lc<DE; lc++){
    int lp = k ? (191 - lc) : lc;
    float xv = xcs[b][lp];
    float xs0 = fmaf(xv, ciw0, cib0);
    float xs1 = fmaf(xv, ciw1, cib1);
    float xs2 = fmaf(xv, ciw2, cib2);
    float xs3 = fmaf(xv, ciw3, cib3);
    float dt = dtb + xs0*EW[0] + xs1*EW[1] + xs2*EW[2] + xs3*EW[3];
    float dl = softplus_f(dt);
    float Bv = xs0*Bw[0] + xs1*Bw[1] + xs2*Bw[2] + xs3*Bw[3];
    float Cv = xs0*Cw[0] + xs1*Cw[1] + xs2*Cw[2] + xs3*Cw[3];
    float u = (dc==0)?xs0:((dc==1)?xs1:((dc==2)?xs2:xs3));
    float dA = __expf(dl * A);
    h = fmaf(h, dA, dl*u*Bv);
    float py = h * Cv;
    py += __shfl_xor(py, 1);
    py += __shfl_xor(py, 2);
    py += __shfl_xor(py, 4);
    py += __shfl_xor(py, 8);
    if (n==0) outc[b][k][dc][lc] = fmaf(Dv, u, py);
  }
  __syncthreads();
  float co0=cout_w[0], co1=cout_w[1], co2=cout_w[2], co3=cout_w[3], cob=cout_b[0];
  for (int i = tid; i < 2*DE; i += 256){
    int bb = i / DE, lc = i % DE;
    float yv = cob
      + co0*(outc[bb][0][0][lc] + outc[bb][1][0][191-lc])
      + co1*(outc[bb][0][1][lc] + outc[bb][1][1][191-lc])
      + co2*(outc[bb][0][2][lc] + outc[bb][1][2][191-lc])
      + co3*(outc[bb][0][3][lc] + outc[bb][1][3][191-lc]);
    ycs[bb][lc] = yv;
  }
  __syncthreads();
  if (tid < 2){
    float s=0.f, s2=0.f;
    for (int lc=0; lc<DE; lc++){ float v=ycs[tid][lc]; s+=v; s2+=v*v; }
    float mu = s/DE; float var = s2/DE - mu*mu;
    stats[tid][0]=mu; stats[tid][1]=rsqrtf(var+1e-5f);
  }
  __syncthreads();
  for (int i = tid; i < 2*DE; i += 256){
    int bb = i / DE, lc = i % DE;
    cvec[i] = (ycs[bb][lc] - stats[bb][0]) * stats[bb][1] * cn_w[lc] + cn_b[lc];
  }
}

// K7: out = conv1x1(y_ln * c * z), 192 -> 96
__global__ __launch_bounds__(256) void k7_out(const float* __restrict__ y_ln,
    const float* __restrict__ cvec, const float* __restrict__ z,
    const float* __restrict__ out_w, const float* __restrict__ out_b,
    float* __restrict__ outp){
  __shared__ float t[DE*16];
  int tile = blockIdx.x;
  int b = tile / 144;
  int pos0 = (tile % 144) * 16;
  int tid = threadIdx.x;
  for (int i = tid; i < DE*16; i += 256){
    int c = i >> 4, p = i & 15;
    int gi = (b*DE + c)*LL + pos0 + p;
    t[c*16 + p] = y_ln[gi] * cvec[b*DE + c] * z[gi];
  }
  __syncthreads();
  for (int j = tid; j < DM*16; j += 256){
    int o = j >> 4, p = j & 15;
    float acc = out_b[o];
    const float* wr = out_w + o*DE;
    #pragma unroll 4
    for (int c=0;c<DE;c++) acc = fmaf(wr[c], t[c*16+p], acc);
    outp[(b*DM + o)*LL + pos0 + p] = acc;
  }
}

extern "C" void kernel_launch(void* const* d_in, const int* in_sizes, int n_in,
                              void* d_out, int out_size, void* d_ws, size_t ws_size,
                              hipStream_t stream){
  const float* x        = (const float*)d_in[0];
  const float* in_w     = (const float*)d_in[1];
  const float* in_b     = (const float*)d_in[2];
  const float* dw_w     = (const float*)d_in[3];
  const float* dw_b     = (const float*)d_in[4];
  const float* x_proj_w = (const float*)d_in[5];
  const float* dt_w     = (const float*)d_in[6];
  const float* dt_b     = (const float*)d_in[7];
  const float* A_logs   = (const float*)d_in[8];
  const float* Ds       = (const float*)d_in[9];
  const float* onw      = (const float*)d_in[10];
  const float* onb      = (const float*)d_in[11];
  const float* cin_w    = (const float*)d_in[12];
  const float* cin_b    = (const float*)d_in[13];
  const float* cout_w   = (const float*)d_in[14];
  const float* cout_b   = (const float*)d_in[15];
  const float* xc_proj_w= (const float*)d_in[16];
  const float* dtc_w    = (const float*)d_in[17];
  const float* dtc_b    = (const float*)d_in[18];
  const float* Ac_logs  = (const float*)d_in[19];
  const float* Dsc      = (const float*)d_in[20];
  const float* cn_w     = (const float*)d_in[21];
  const float* cn_b     = (const float*)d_in[22];
  const float* out_w    = (const float*)d_in[23];
  const float* out_b    = (const float*)d_in[24];

  float* ws = (float*)d_ws;
  float* x1raw = ws;  ws += 2*DE*LL;
  float* zbuf  = ws;  ws += 2*DE*LL;
  float* xconv = ws;  ws += 2*DE*LL;
  float* delta = ws;  ws += 2*4*DE*LL;
  float* Bsb   = ws;  ws += 2*4*LL*NS;
  float* Csb   = ws;  ws += 2*4*LL*NS;
  float* outy  = ws;  ws += 2*4*DE*LL;
  float* yln   = ws;  ws += 2*DE*LL;
  float* cvec  = ws;  ws += 2*DE;
  float* partial = ws; ws += 2*144*DE;
  float* xconvT = yln;   // alias: xconvT dead before k5 writes yln

  hipLaunchKernelGGL(k1_conv_in, dim3(288), dim3(384), 0, stream, x, in_w, in_b, x1raw, zbuf);
  hipLaunchKernelGGL(k2_dwconv, dim3(384), dim3(256), 0, stream, x1raw, dw_w, dw_b, xconv, xconvT);
  hipLaunchKernelGGL(k3_proj, dim3(288), dim3(256), 0, stream, xconv, xconvT, x_proj_w, dt_w, dt_b, delta, Bsb, Csb);
  hipLaunchKernelGGL(k4_scan, dim3(1536), dim3(256), 0, stream, xconv, xconvT, delta, Bsb, Csb, A_logs, Ds, outy);
  hipLaunchKernelGGL(k5_combine_ln, dim3(288), dim3(256), 0, stream, outy, onw, onb, yln, partial);
  hipLaunchKernelGGL(k6b_channel, dim3(1), dim3(256), 0, stream, partial, cin_w, cin_b, cout_w, cout_b,
                     xc_proj_w, dtc_w, dtc_b, Ac_logs, Dsc, cn_w, cn_b, cvec);
  hipLaunchKernelGGL(k7_out, dim3(288), dim3(256), 0, stream, yln, cvec, zbuf, out_w, out_b, (float*)d_out);
}

// Round 5
// 202.446 us; speedup vs baseline: 6.5101x; 1.5342x over previous
//
#include <hip/hip_runtime.h>
#include <math.h>

#define DM 96
#define DE 192
#define LL 2304
#define NS 16
#define RK 6
#define NC 38   // RK + 2*NS
#define CH4 64  // scan chunks (k4)
#define CL4 36  // 2304/64

__device__ __forceinline__ float silu_f(float x){ return x / (1.f + __expf(-x)); }
// fast softplus: log1pf is a slow libm call; __logf/__expf are HW instrs.
__device__ __forceinline__ float softplus_f(float x){
  return (x > 20.f) ? x : __logf(1.f + __expf(x));
}

// xs[b,k,d,l] = xconv[b,d,dir_map(k,l)]
__device__ __forceinline__ int dir_map(int k, int l){
    switch(k){
      case 0: return l;
      case 1: return (l % 48) * 48 + l / 48;
      case 2: return 2303 - l;
      default: { int lr = 2303 - l; return (lr % 48) * 48 + lr / 48; }
    }
}

// K1: 1x1 conv in (96 -> 384), split into x1raw (first 192) and z=silu (last 192)
__global__ __launch_bounds__(384) void k1_conv_in(const float* __restrict__ x,
    const float* __restrict__ in_w, const float* __restrict__ in_b,
    float* __restrict__ x1raw, float* __restrict__ z){
  __shared__ float xv[DM*16];
  int tile = blockIdx.x;
  int b = tile / 144;
  int pos0 = (tile % 144) * 16;
  int tid = threadIdx.x;
  for (int i = tid; i < DM*16; i += 384){
    int c = i >> 4, p = i & 15;
    xv[c*16 + p] = x[(b*DM + c)*LL + pos0 + p];
  }
  __syncthreads();
  float acc[16];
  #pragma unroll
  for (int p=0;p<16;p++) acc[p] = in_b[tid];
  for (int c=0;c<DM;c++){
    float w = in_w[tid*DM + c];
    #pragma unroll
    for (int p=0;p<16;p++) acc[p] = fmaf(w, xv[c*16+p], acc[p]);
  }
  if (tid < DE){
    #pragma unroll
    for (int p=0;p<16;p++) x1raw[(b*DE + tid)*LL + pos0 + p] = acc[p];
  } else {
    int zc = tid - DE;
    #pragma unroll
    for (int p=0;p<16;p++) z[(b*DE + zc)*LL + pos0 + p] = silu_f(acc[p]);
  }
}

// K2: depthwise 3x3 + silu via LDS plane; emits xconv AND xconvT (transposed).
__global__ __launch_bounds__(256) void k2_dwconv(const float* __restrict__ x1raw,
    const float* __restrict__ dw_w, const float* __restrict__ dw_b,
    float* __restrict__ xconv, float* __restrict__ xconvT){
  __shared__ float lin[50][52];
  __shared__ float lout[48][50];
  int bd = blockIdx.x;        // b*DE + d
  int d = bd % DE;
  int tid = threadIdx.x;
  for (int i = tid; i < 50*52; i += 256) ((float*)lin)[i] = 0.f;
  __syncthreads();
  const float* src = x1raw + bd*LL;
  for (int i = tid; i < LL; i += 256){
    lin[i/48 + 1][i%48 + 1] = src[i];
  }
  float w00=dw_w[d*9+0], w01=dw_w[d*9+1], w02=dw_w[d*9+2];
  float w10=dw_w[d*9+3], w11=dw_w[d*9+4], w12=dw_w[d*9+5];
  float w20=dw_w[d*9+6], w21=dw_w[d*9+7], w22=dw_w[d*9+8];
  float bias = dw_b[d];
  __syncthreads();
  float* dst = xconv + bd*LL;
  for (int i = tid; i < LL; i += 256){
    int h = i/48, w = i%48;
    float acc = bias;
    acc = fmaf(w00, lin[h  ][w], fmaf(w01, lin[h  ][w+1], fmaf(w02, lin[h  ][w+2], acc)));
    acc = fmaf(w10, lin[h+1][w], fmaf(w11, lin[h+1][w+1], fmaf(w12, lin[h+1][w+2], acc)));
    acc = fmaf(w20, lin[h+2][w], fmaf(w21, lin[h+2][w+1], fmaf(w22, lin[h+2][w+2], acc)));
    float v = silu_f(acc);
    dst[i] = v;
    lout[h][w] = v;
  }
  __syncthreads();
  float* dstT = xconvT + bd*LL;
  for (int i = tid; i < LL; i += 256){
    int tw = i/48, th = i%48;   // T[w*48+h] = X[h*48+w]
    dstT[i] = lout[th][tw];
  }
}

// K3: d-split projection (uses xconvT for coalesced odd-k reads).
__global__ __launch_bounds__(256) void k3_proj(const float* __restrict__ xconv,
    const float* __restrict__ xconvT,
    const float* __restrict__ x_proj_w, const float* __restrict__ dt_w,
    const float* __restrict__ dt_b, float* __restrict__ delta,
    float* __restrict__ Bs, float* __restrict__ Cs){
  __shared__ float smem[38*256];
  int bk = blockIdx.x / 36;
  int tile = blockIdx.x % 36;
  int b = bk >> 2, k = bk & 3;
  int tid = threadIdx.x;
  int lsub = tid & 63, dgrp = tid >> 6;
  int l = tile*64 + lsub;
  const float* wsrc = x_proj_w + k*NC*DE;
  for (int idx = tid; idx < NC*DE; idx += 256){
    int c = idx / DE, d = idx % DE;
    smem[d*40 + c] = wsrc[idx];
  }
  if (tid < DE){ smem[tid*40 + 38] = 0.f; smem[tid*40 + 39] = 0.f; }
  __syncthreads();
  float acc[40];
  #pragma unroll
  for (int c=0;c<40;c++) acc[c]=0.f;
  const float* uptr;
  {
    const float* basep = (k & 1) ? (xconvT + b*DE*LL) : (xconv + b*DE*LL);
    uptr = basep + ((k >= 2) ? (2303 - l) : l);
  }
  for (int dd=0; dd<48; dd++){
    int d = dgrp*48 + dd;
    float u = uptr[d*LL];
    const float4* wrow = (const float4*)&smem[d*40];
    #pragma unroll
    for (int j=0;j<10;j++){
      float4 wv = wrow[j];
      acc[j*4+0] = fmaf(u, wv.x, acc[j*4+0]);
      acc[j*4+1] = fmaf(u, wv.y, acc[j*4+1]);
      acc[j*4+2] = fmaf(u, wv.z, acc[j*4+2]);
      acc[j*4+3] = fmaf(u, wv.w, acc[j*4+3]);
    }
  }
  __syncthreads();
  #pragma unroll
  for (int c=0;c<38;c++) smem[c*256 + dgrp*64 + lsub] = acc[c];
  __syncthreads();
  for (int idx = tid; idx < 38*64; idx += 256){
    int c = idx >> 6, l2 = idx & 63;
    float s = smem[c*256 + l2] + smem[c*256 + 64 + l2]
            + smem[c*256 + 128 + l2] + smem[c*256 + 192 + l2];
    int lg = tile*64 + l2;
    if (c < RK){
      smem[c*256 + l2] = s;
    } else if (c < RK + NS){
      Bs[(bk*LL + lg)*NS + (c - RK)] = s;
    } else {
      Cs[(bk*LL + lg)*NS + (c - RK - NS)] = s;
    }
  }
  __syncthreads();
  float r0 = smem[0*256 + lsub], r1 = smem[1*256 + lsub], r2 = smem[2*256 + lsub];
  float r3 = smem[3*256 + lsub], r4 = smem[4*256 + lsub], r5 = smem[5*256 + lsub];
  const float* dwb = dt_w + k*DE*RK;
  const float* dbb = dt_b + k*DE;
  for (int dd=0; dd<48; dd++){
    int d = dgrp*48 + dd;
    const float* wr = dwb + d*RK;
    float t = dbb[d];
    t = fmaf(r0, wr[0], t); t = fmaf(r1, wr[1], t); t = fmaf(r2, wr[2], t);
    t = fmaf(r3, wr[3], t); t = fmaf(r4, wr[4], t); t = fmaf(r5, wr[5], t);
    delta[(bk*DE + d)*LL + l] = softplus_f(t);
  }
}

// K4: chunked scan, lane = (chunk c of 64, n-quad q of 4), all float4 loads.
__global__ __launch_bounds__(256) void k4_scan(const float* __restrict__ xconv,
    const float* __restrict__ xconvT,
    const float* __restrict__ delta, const float* __restrict__ Bs,
    const float* __restrict__ Cs, const float* __restrict__ A_logs,
    const float* __restrict__ Ds, float* __restrict__ out_y){
  int gid = blockIdx.x;           // [0, 1536)
  int b = gid / (4*DE);
  int kd = gid % (4*DE);
  int k = kd / DE;
  int d = kd % DE;
  int bk = b*4 + k;
  int tid = threadIdx.x;
  int c = tid >> 2, q = tid & 3;
  const float LOG2E = 1.44269504f;
  float4 al = *(const float4*)&A_logs[(k*DE + d)*NS + q*4];
  float A2[4];
  A2[0] = -__expf(al.x)*LOG2E; A2[1] = -__expf(al.y)*LOG2E;
  A2[2] = -__expf(al.z)*LOG2E; A2[3] = -__expf(al.w)*LOG2E;
  float Dv = Ds[k*DE + d];
  const float* dptr = delta + (bk*DE + d)*LL;
  const float* ub = ((k & 1) ? xconvT : xconv) + (b*DE + d)*LL;
  bool rev = (k >= 2);
  const float* bbase = Bs + bk*LL*NS + q*4;
  const float* cbase = Cs + bk*LL*NS + q*4;
  float* optr = out_y + (bk*DE + d)*LL;
  int l0 = c*CL4;
  // Phase A: local (P, S) per chunk
  float P[4] = {1.f,1.f,1.f,1.f}, S[4] = {0.f,0.f,0.f,0.f};
  for (int i=0;i<CL4;i+=4){
    int l = l0 + i;
    float4 dl4 = *(const float4*)(dptr + l);
    float4 u4;
    if (!rev) u4 = *(const float4*)(ub + l);
    else { float4 t = *(const float4*)(ub + (LL-4) - l); u4 = make_float4(t.w,t.z,t.y,t.x); }
    #pragma unroll
    for (int j=0;j<4;j++){
      float dlj = (j==0)?dl4.x:((j==1)?dl4.y:((j==2)?dl4.z:dl4.w));
      float uj  = (j==0)?u4.x:((j==1)?u4.y:((j==2)?u4.z:u4.w));
      float du = dlj*uj;
      float4 Bv = *(const float4*)(bbase + (l+j)*NS);
      float dA0 = exp2f(dlj*A2[0]); S[0] = fmaf(S[0], dA0, du*Bv.x); P[0]*=dA0;
      float dA1 = exp2f(dlj*A2[1]); S[1] = fmaf(S[1], dA1, du*Bv.y); P[1]*=dA1;
      float dA2 = exp2f(dlj*A2[2]); S[2] = fmaf(S[2], dA2, du*Bv.z); P[2]*=dA2;
      float dA3 = exp2f(dlj*A2[3]); S[3] = fmaf(S[3], dA3, du*Bv.w); P[3]*=dA3;
    }
  }
  __shared__ float sP[CH4][NS], sS[CH4][NS];
  *(float4*)&sP[c][q*4] = make_float4(P[0],P[1],P[2],P[3]);
  *(float4*)&sS[c][q*4] = make_float4(S[0],S[1],S[2],S[3]);
  __syncthreads();
  // Phase B: 16 threads, serial combine over 64 chunks
  if (tid < NS){
    float hacc = 0.f;
    #pragma unroll 4
    for (int cc=0; cc<CH4; cc++){
      hacc = fmaf(hacc, sP[cc][tid], sS[cc][tid]);
      sS[cc][tid] = hacc;
    }
  }
  __syncthreads();
  float h[4];
  if (c == 0){ h[0]=h[1]=h[2]=h[3]=0.f; }
  else { float4 hi = *(const float4*)&sS[c-1][q*4]; h[0]=hi.x; h[1]=hi.y; h[2]=hi.z; h[3]=hi.w; }
  // Phase C: rescan + output (spatial order)
  for (int i=0;i<CL4;i+=4){
    int l = l0 + i;
    float4 dl4 = *(const float4*)(dptr + l);
    float4 u4;
    if (!rev) u4 = *(const float4*)(ub + l);
    else { float4 t = *(const float4*)(ub + (LL-4) - l); u4 = make_float4(t.w,t.z,t.y,t.x); }
    #pragma unroll
    for (int j=0;j<4;j++){
      float dlj = (j==0)?dl4.x:((j==1)?dl4.y:((j==2)?dl4.z:dl4.w));
      float uj  = (j==0)?u4.x:((j==1)?u4.y:((j==2)?u4.z:u4.w));
      float du = dlj*uj;
      float4 Bv = *(const float4*)(bbase + (l+j)*NS);
      float4 Cv = *(const float4*)(cbase + (l+j)*NS);
      float dA0 = exp2f(dlj*A2[0]); h[0] = fmaf(h[0], dA0, du*Bv.x);
      float dA1 = exp2f(dlj*A2[1]); h[1] = fmaf(h[1], dA1, du*Bv.y);
      float dA2 = exp2f(dlj*A2[2]); h[2] = fmaf(h[2], dA2, du*Bv.z);
      float dA3 = exp2f(dlj*A2[3]); h[3] = fmaf(h[3], dA3, du*Bv.w);
      float py = h[0]*Cv.x + h[1]*Cv.y + h[2]*Cv.z + h[3]*Cv.w;
      py += __shfl_xor(py, 1);
      py += __shfl_xor(py, 2);
      if (q == 0){
        int pos = dir_map(k, l+j);
        optr[pos] = fmaf(Dv, uj, py);
      }
    }
  }
}

// K5: combine 4 dirs + channel LN; also emit per-tile channel partial sums.
__global__ __launch_bounds__(256) void k5_combine_ln(const float* __restrict__ out_y,
    const float* __restrict__ onw, const float* __restrict__ onb,
    float* __restrict__ y_ln, float* __restrict__ partial){
  __shared__ float vals[DE][17];
  __shared__ float s_[16][16], s2_[16][16];
  __shared__ float mu_[16], rs_[16];
  int bT = blockIdx.x;               // [0, 288) = b*144 + tile
  int b = bT / 144;
  int pos0 = (bT % 144) * 16;
  int tid = threadIdx.x;
  int p = tid & 15, g = tid >> 4;
  const float* base = out_y + b*4*DE*LL;
  float s = 0.f, s2 = 0.f;
  #pragma unroll
  for (int j=0;j<12;j++){
    int d = g*12 + j;
    int idx = d*LL + pos0 + p;
    float v = base[idx] + base[DE*LL + idx] + base[2*DE*LL + idx] + base[3*DE*LL + idx];
    vals[d][p] = v;
    s += v; s2 += v*v;
  }
  s_[g][p] = s; s2_[g][p] = s2;
  __syncthreads();
  if (tid < 16){
    float ss = 0.f, ss2 = 0.f;
    #pragma unroll
    for (int gg=0; gg<16; gg++){ ss += s_[gg][tid]; ss2 += s2_[gg][tid]; }
    float mu = ss / DE;
    float var = ss2 / DE - mu*mu;
    mu_[tid] = mu; rs_[tid] = rsqrtf(var + 1e-5f);
  }
  __syncthreads();
  float mu = mu_[p], rs = rs_[p];
  #pragma unroll
  for (int j=0;j<12;j++){
    int d = g*12 + j;
    float yv = (vals[d][p] - mu)*rs*onw[d] + onb[d];
    y_ln[(b*DE + d)*LL + pos0 + p] = yv;
    vals[d][p] = yv;
  }
  __syncthreads();
  if (tid < DE){
    float ps = 0.f;
    #pragma unroll
    for (int pp=0;pp<16;pp++) ps += vals[tid][pp];
    partial[bT*DE + tid] = ps;
  }
}

// K6b v3: channel core, chunked scan. grid=2 (one block per b), 512 threads.
// chain = (k,dc,n) -> 128 chains x 4 chunks of 48. lane = n*4+ch within wave,
// so the n-reduction is shfl_xor {4,8,16,32}.
__global__ __launch_bounds__(512) void k6b_channel(const float* __restrict__ partial,
    const float* __restrict__ cin_w, const float* __restrict__ cin_b,
    const float* __restrict__ cout_w, const float* __restrict__ cout_b,
    const float* __restrict__ xc_proj_w, const float* __restrict__ dtc_w,
    const float* __restrict__ dtc_b, const float* __restrict__ Ac_logs,
    const float* __restrict__ Dsc, const float* __restrict__ cn_w,
    const float* __restrict__ cn_b, float* __restrict__ cvec){
  __shared__ float xcs[DE];
  __shared__ float tmp[384];
  __shared__ float sP[128][4], sS[128][4];
  __shared__ float outc[2][4][DE];
  __shared__ float ycs[DE];
  __shared__ float muS, rsS;
  int b = blockIdx.x;
  int tid = threadIdx.x;
  // xc reduction: 192 d's x 2 halves of 72 tiles
  if (tid < 384){
    int d = tid % DE, half = tid / DE;
    const float* pp = partial + (b*144 + half*72)*DE + d;
    float sacc = 0.f;
    #pragma unroll 8
    for (int t=0;t<72;t++) sacc += pp[t*DE];
    tmp[tid] = sacc;
  }
  __syncthreads();
  if (tid < DE) xcs[tid] = (tmp[tid] + tmp[tid + DE]) * (1.f/LL);
  __syncthreads();
  int chain = tid >> 2, ch = tid & 3;
  int k = chain >> 6, dc = (chain >> 4) & 3, n = chain & 15;
  const float LOG2E = 1.44269504f;
  float EW0=0,EW1=0,EW2=0,EW3=0;
  #pragma unroll
  for (int r=0;r<RK;r++){
    float dw = dtc_w[(k*4+dc)*RK + r];
    EW0 = fmaf(dw, xc_proj_w[(k*NC + r)*4 + 0], EW0);
    EW1 = fmaf(dw, xc_proj_w[(k*NC + r)*4 + 1], EW1);
    EW2 = fmaf(dw, xc_proj_w[(k*NC + r)*4 + 2], EW2);
    EW3 = fmaf(dw, xc_proj_w[(k*NC + r)*4 + 3], EW3);
  }
  float Bw0 = xc_proj_w[(k*NC + RK + n)*4 + 0];
  float Bw1 = xc_proj_w[(k*NC + RK + n)*4 + 1];
  float Bw2 = xc_proj_w[(k*NC + RK + n)*4 + 2];
  float Bw3 = xc_proj_w[(k*NC + RK + n)*4 + 3];
  float Cw0 = xc_proj_w[(k*NC + RK + NS + n)*4 + 0];
  float Cw1 = xc_proj_w[(k*NC + RK + NS + n)*4 + 1];
  float Cw2 = xc_proj_w[(k*NC + RK + NS + n)*4 + 2];
  float Cw3 = xc_proj_w[(k*NC + RK + NS + n)*4 + 3];
  float A2 = -__expf(Ac_logs[(k*4+dc)*NS + n]) * LOG2E;
  float Dv = Dsc[k*4+dc];
  float dtb = dtc_b[k*4+dc];
  float ciw0=cin_w[0], ciw1=cin_w[1], ciw2=cin_w[2], ciw3=cin_w[3];
  float cib0=cin_b[0], cib1=cin_b[1], cib2=cin_b[2], cib3=cin_b[3];
  int l0 = ch*48;
  // Phase A
  float P = 1.f, S = 0.f;
  for (int i=0;i<48;i++){
    int lc = l0 + i;
    int lp = k ? (191 - lc) : lc;
    float xv = xcs[lp];
    float xs0 = fmaf(xv, ciw0, cib0);
    float xs1 = fmaf(xv, ciw1, cib1);
    float xs2 = fmaf(xv, ciw2, cib2);
    float xs3 = fmaf(xv, ciw3, cib3);
    float dt = dtb + xs0*EW0 + xs1*EW1 + xs2*EW2 + xs3*EW3;
    float dl = softplus_f(dt);
    float Bv = xs0*Bw0 + xs1*Bw1 + xs2*Bw2 + xs3*Bw3;
    float u = (dc==0)?xs0:((dc==1)?xs1:((dc==2)?xs2:xs3));
    float dA = exp2f(dl * A2);
    S = fmaf(S, dA, dl*u*Bv);
    P *= dA;
  }
  sP[chain][ch] = P; sS[chain][ch] = S;
  __syncthreads();
  if (tid < 128){
    float hacc = 0.f;
    #pragma unroll
    for (int cc=0; cc<4; cc++){
      hacc = fmaf(hacc, sP[tid][cc], sS[tid][cc]);
      sS[tid][cc] = hacc;
    }
  }
  __syncthreads();
  float h = (ch == 0) ? 0.f : sS[chain][ch-1];
  // Phase C
  for (int i=0;i<48;i++){
    int lc = l0 + i;
    int lp = k ? (191 - lc) : lc;
    float xv = xcs[lp];
    float xs0 = fmaf(xv, ciw0, cib0);
    float xs1 = fmaf(xv, ciw1, cib1);
    float xs2 = fmaf(xv, ciw2, cib2);
    float xs3 = fmaf(xv, ciw3, cib3);
    float dt = dtb + xs0*EW0 + xs1*EW1 + xs2*EW2 + xs3*EW3;
    float dl = softplus_f(dt);
    float Bv = xs0*Bw0 + xs1*Bw1 + xs2*Bw2 + xs3*Bw3;
    float Cv = xs0*Cw0 + xs1*Cw1 + xs2*Cw2 + xs3*Cw3;
    float u = (dc==0)?xs0:((dc==1)?xs1:((dc==2)?xs2:xs3));
    float dA = exp2f(dl * A2);
    h = fmaf(h, dA, dl*u*Bv);
    float py = h * Cv;
    py += __shfl_xor(py, 4);
    py += __shfl_xor(py, 8);
    py += __shfl_xor(py, 16);
    py += __shfl_xor(py, 32);
    if (n == 0) outc[k][dc][lc] = fmaf(Dv, u, py);
  }
  __syncthreads();
  float co0=cout_w[0], co1=cout_w[1], co2=cout_w[2], co3=cout_w[3], cob=cout_b[0];
  for (int i = tid; i < DE; i += 512){
    float yv = cob
      + co0*(outc[0][0][i] + outc[1][0][191-i])
      + co1*(outc[0][1][i] + outc[1][1][191-i])
      + co2*(outc[0][2][i] + outc[1][2][191-i])
      + co3*(outc[0][3][i] + outc[1][3][191-i]);
    ycs[i] = yv;
  }
  __syncthreads();
  if (tid < 64){
    float s = 0.f, s2 = 0.f;
    #pragma unroll
    for (int j=0;j<3;j++){
      float v = ycs[tid + j*64];
      s += v; s2 += v*v;
    }
    for (int off=32; off>0; off>>=1){ s += __shfl_down(s, off); s2 += __shfl_down(s2, off); }
    if (tid == 0){
      float mu = s / DE;
      float var = s2 / DE - mu*mu;
      muS = mu; rsS = rsqrtf(var + 1e-5f);
    }
  }
  __syncthreads();
  float mu = muS, rs = rsS;
  for (int i = tid; i < DE; i += 512){
    cvec[b*DE + i] = (ycs[i] - mu) * rs * cn_w[i] + cn_b[i];
  }
}

// K7: out = conv1x1(y_ln * c * z), 192 -> 96
__global__ __launch_bounds__(256) void k7_out(const float* __restrict__ y_ln,
    const float* __restrict__ cvec, const float* __restrict__ z,
    const float* __restrict__ out_w, const float* __restrict__ out_b,
    float* __restrict__ outp){
  __shared__ float t[DE*16];
  int tile = blockIdx.x;
  int b = tile / 144;
  int pos0 = (tile % 144) * 16;
  int tid = threadIdx.x;
  for (int i = tid; i < DE*16; i += 256){
    int c = i >> 4, p = i & 15;
    int gi = (b*DE + c)*LL + pos0 + p;
    t[c*16 + p] = y_ln[gi] * cvec[b*DE + c] * z[gi];
  }
  __syncthreads();
  for (int j = tid; j < DM*16; j += 256){
    int o = j >> 4, p = j & 15;
    float acc = out_b[o];
    const float* wr = out_w + o*DE;
    #pragma unroll 4
    for (int c=0;c<DE;c++) acc = fmaf(wr[c], t[c*16+p], acc);
    outp[(b*DM + o)*LL + pos0 + p] = acc;
  }
}

extern "C" void kernel_launch(void* const* d_in, const int* in_sizes, int n_in,
                              void* d_out, int out_size, void* d_ws, size_t ws_size,
                              hipStream_t stream){
  const float* x        = (const float*)d_in[0];
  const float* in_w     = (const float*)d_in[1];
  const float* in_b     = (const float*)d_in[2];
  const float* dw_w     = (const float*)d_in[3];
  const float* dw_b     = (const float*)d_in[4];
  const float* x_proj_w = (const float*)d_in[5];
  const float* dt_w     = (const float*)d_in[6];
  const float* dt_b     = (const float*)d_in[7];
  const float* A_logs   = (const float*)d_in[8];
  const float* Ds       = (const float*)d_in[9];
  const float* onw      = (const float*)d_in[10];
  const float* onb      = (const float*)d_in[11];
  const float* cin_w    = (const float*)d_in[12];
  const float* cin_b    = (const float*)d_in[13];
  const float* cout_w   = (const float*)d_in[14];
  const float* cout_b   = (const float*)d_in[15];
  const float* xc_proj_w= (const float*)d_in[16];
  const float* dtc_w    = (const float*)d_in[17];
  const float* dtc_b    = (const float*)d_in[18];
  const float* Ac_logs  = (const float*)d_in[19];
  const float* Dsc      = (const float*)d_in[20];
  const float* cn_w     = (const float*)d_in[21];
  const float* cn_b     = (const float*)d_in[22];
  const float* out_w    = (const float*)d_in[23];
  const float* out_b    = (const float*)d_in[24];

  float* ws = (float*)d_ws;
  float* x1raw = ws;  ws += 2*DE*LL;
  float* zbuf  = ws;  ws += 2*DE*LL;
  float* xconv = ws;  ws += 2*DE*LL;
  float* delta = ws;  ws += 2*4*DE*LL;
  float* Bsb   = ws;  ws += 2*4*LL*NS;
  float* Csb   = ws;  ws += 2*4*LL*NS;
  float* outy  = ws;  ws += 2*4*DE*LL;
  float* yln   = ws;  ws += 2*DE*LL;
  float* cvec  = ws;  ws += 2*DE;
  float* partial = ws; ws += 2*144*DE;
  float* xconvT = yln;   // alias: xconvT dead before k5 writes yln

  hipLaunchKernelGGL(k1_conv_in, dim3(288), dim3(384), 0, stream, x, in_w, in_b, x1raw, zbuf);
  hipLaunchKernelGGL(k2_dwconv, dim3(384), dim3(256), 0, stream, x1raw, dw_w, dw_b, xconv, xconvT);
  hipLaunchKernelGGL(k3_proj, dim3(288), dim3(256), 0, stream, xconv, xconvT, x_proj_w, dt_w, dt_b, delta, Bsb, Csb);
  hipLaunchKernelGGL(k4_scan, dim3(1536), dim3(256), 0, stream, xconv, xconvT, delta, Bsb, Csb, A_logs, Ds, outy);
  hipLaunchKernelGGL(k5_combine_ln, dim3(288), dim3(256), 0, stream, outy, onw, onb, yln, partial);
  hipLaunchKernelGGL(k6b_channel, dim3(2), dim3(512), 0, stream, partial, cin_w, cin_b, cout_w, cout_b,
                     xc_proj_w, dtc_w, dtc_b, Ac_logs, Dsc, cn_w, cn_b, cvec);
  hipLaunchKernelGGL(k7_out, dim3(288), dim3(256), 0, stream, yln, cvec, zbuf, out_w, out_b, (float*)d_out);
}

// Round 6
// 185.552 us; speedup vs baseline: 7.1028x; 1.0910x over previous
//
#include <hip/hip_runtime.h>
#include <math.h>

#define DM 96
#define DE 192
#define LL 2304
#define NS 16
#define RK 6
#define NC 38   // RK + 2*NS
#define CH4 64  // scan chunks (k4)
#define CL4 36  // 2304/64

__device__ __forceinline__ float silu_f(float x){ return x / (1.f + __expf(-x)); }
// fast softplus: log1pf is a slow libm call; __logf/__expf are HW instrs.
__device__ __forceinline__ float softplus_f(float x){
  return (x > 20.f) ? x : __logf(1.f + __expf(x));
}

// xs[b,k,d,l] = xconv[b,d,dir_map(k,l)]
__device__ __forceinline__ int dir_map(int k, int l){
    switch(k){
      case 0: return l;
      case 1: return (l % 48) * 48 + l / 48;
      case 2: return 2303 - l;
      default: { int lr = 2303 - l; return (lr % 48) * 48 + lr / 48; }
    }
}

// K1: 1x1 conv in (96 -> 384), split into x1raw (first 192) and z=silu (last 192)
__global__ __launch_bounds__(384) void k1_conv_in(const float* __restrict__ x,
    const float* __restrict__ in_w, const float* __restrict__ in_b,
    float* __restrict__ x1raw, float* __restrict__ z){
  __shared__ float xv[DM*16];
  int tile = blockIdx.x;
  int b = tile / 144;
  int pos0 = (tile % 144) * 16;
  int tid = threadIdx.x;
  {  // stage 96 channels x 16 px as float4 (one per thread)
    int c = tid >> 2, p4 = tid & 3;
    float4 v = *(const float4*)(x + (b*DM + c)*LL + pos0 + p4*4);
    *(float4*)&xv[c*16 + p4*4] = v;
  }
  __syncthreads();
  float acc[16];
  #pragma unroll
  for (int p=0;p<16;p++) acc[p] = in_b[tid];
  const float4* wv4 = (const float4*)(in_w + tid*DM);
  #pragma unroll 4
  for (int c4=0;c4<24;c4++){
    float4 wv = wv4[c4];
    #pragma unroll
    for (int cc=0;cc<4;cc++){
      float w = (cc==0)?wv.x:((cc==1)?wv.y:((cc==2)?wv.z:wv.w));
      const float* xr = &xv[(c4*4+cc)*16];
      #pragma unroll
      for (int p4=0;p4<4;p4++){
        float4 xq = *(const float4*)&xr[p4*4];
        acc[p4*4+0] = fmaf(w, xq.x, acc[p4*4+0]);
        acc[p4*4+1] = fmaf(w, xq.y, acc[p4*4+1]);
        acc[p4*4+2] = fmaf(w, xq.z, acc[p4*4+2]);
        acc[p4*4+3] = fmaf(w, xq.w, acc[p4*4+3]);
      }
    }
  }
  if (tid < DE){
    float* dst = x1raw + (b*DE + tid)*LL + pos0;
    #pragma unroll
    for (int p4=0;p4<4;p4++)
      *(float4*)(dst + p4*4) = make_float4(acc[p4*4+0],acc[p4*4+1],acc[p4*4+2],acc[p4*4+3]);
  } else {
    int zc = tid - DE;
    float* dst = z + (b*DE + zc)*LL + pos0;
    #pragma unroll
    for (int p4=0;p4<4;p4++)
      *(float4*)(dst + p4*4) = make_float4(silu_f(acc[p4*4+0]),silu_f(acc[p4*4+1]),
                                           silu_f(acc[p4*4+2]),silu_f(acc[p4*4+3]));
  }
}

// K2: depthwise 3x3 + silu via LDS plane; emits xconv AND xconvT (transposed).
__global__ __launch_bounds__(256) void k2_dwconv(const float* __restrict__ x1raw,
    const float* __restrict__ dw_w, const float* __restrict__ dw_b,
    float* __restrict__ xconv, float* __restrict__ xconvT){
  __shared__ float lin[50][52];
  __shared__ float lout[48][50];
  int bd = blockIdx.x;        // b*DE + d
  int d = bd % DE;
  int tid = threadIdx.x;
  for (int i = tid; i < 50*52; i += 256) ((float*)lin)[i] = 0.f;
  __syncthreads();
  const float* src = x1raw + bd*LL;
  for (int i = tid; i < 576; i += 256){
    int r = i/12, c4 = (i%12)*4;
    float4 v = *(const float4*)(src + r*48 + c4);
    lin[r+1][c4+1] = v.x; lin[r+1][c4+2] = v.y; lin[r+1][c4+3] = v.z; lin[r+1][c4+4] = v.w;
  }
  float w00=dw_w[d*9+0], w01=dw_w[d*9+1], w02=dw_w[d*9+2];
  float w10=dw_w[d*9+3], w11=dw_w[d*9+4], w12=dw_w[d*9+5];
  float w20=dw_w[d*9+6], w21=dw_w[d*9+7], w22=dw_w[d*9+8];
  float bias = dw_b[d];
  __syncthreads();
  float* dst = xconv + bd*LL;
  for (int i = tid; i < 576; i += 256){
    int h = i/12, w4 = (i%12)*4;
    float o[4];
    #pragma unroll
    for (int j=0;j<4;j++){
      int w = w4 + j;
      float acc = bias;
      acc = fmaf(w00, lin[h  ][w], fmaf(w01, lin[h  ][w+1], fmaf(w02, lin[h  ][w+2], acc)));
      acc = fmaf(w10, lin[h+1][w], fmaf(w11, lin[h+1][w+1], fmaf(w12, lin[h+1][w+2], acc)));
      acc = fmaf(w20, lin[h+2][w], fmaf(w21, lin[h+2][w+1], fmaf(w22, lin[h+2][w+2], acc)));
      float v = silu_f(acc);
      o[j] = v;
      lout[h][w] = v;
    }
    *(float4*)(dst + h*48 + w4) = make_float4(o[0],o[1],o[2],o[3]);
  }
  __syncthreads();
  float* dstT = xconvT + bd*LL;
  for (int i = tid; i < 576; i += 256){
    int tw = i/12, th4 = (i%12)*4;
    float4 v = make_float4(lout[th4][tw], lout[th4+1][tw], lout[th4+2][tw], lout[th4+3][tw]);
    *(float4*)(dstT + tw*48 + th4) = v;
  }
}

// K3: d-split projection (uses xconvT for coalesced odd-k reads).
__global__ __launch_bounds__(256) void k3_proj(const float* __restrict__ xconv,
    const float* __restrict__ xconvT,
    const float* __restrict__ x_proj_w, const float* __restrict__ dt_w,
    const float* __restrict__ dt_b, float* __restrict__ delta,
    float* __restrict__ Bs, float* __restrict__ Cs){
  __shared__ float smem[38*256];
  int bk = blockIdx.x / 36;
  int tile = blockIdx.x % 36;
  int b = bk >> 2, k = bk & 3;
  int tid = threadIdx.x;
  int lsub = tid & 63, dgrp = tid >> 6;
  int l = tile*64 + lsub;
  const float* wsrc = x_proj_w + k*NC*DE;
  for (int idx = tid; idx < NC*DE; idx += 256){
    int c = idx / DE, d = idx % DE;
    smem[d*40 + c] = wsrc[idx];
  }
  if (tid < DE){ smem[tid*40 + 38] = 0.f; smem[tid*40 + 39] = 0.f; }
  __syncthreads();
  float acc[40];
  #pragma unroll
  for (int c=0;c<40;c++) acc[c]=0.f;
  const float* uptr;
  {
    const float* basep = (k & 1) ? (xconvT + b*DE*LL) : (xconv + b*DE*LL);
    uptr = basep + ((k >= 2) ? (2303 - l) : l);
  }
  for (int dd=0; dd<48; dd++){
    int d = dgrp*48 + dd;
    float u = uptr[d*LL];
    const float4* wrow = (const float4*)&smem[d*40];
    #pragma unroll
    for (int j=0;j<10;j++){
      float4 wv = wrow[j];
      acc[j*4+0] = fmaf(u, wv.x, acc[j*4+0]);
      acc[j*4+1] = fmaf(u, wv.y, acc[j*4+1]);
      acc[j*4+2] = fmaf(u, wv.z, acc[j*4+2]);
      acc[j*4+3] = fmaf(u, wv.w, acc[j*4+3]);
    }
  }
  __syncthreads();
  #pragma unroll
  for (int c=0;c<38;c++) smem[c*256 + dgrp*64 + lsub] = acc[c];
  __syncthreads();
  for (int idx = tid; idx < 38*64; idx += 256){
    int c = idx >> 6, l2 = idx & 63;
    float s = smem[c*256 + l2] + smem[c*256 + 64 + l2]
            + smem[c*256 + 128 + l2] + smem[c*256 + 192 + l2];
    int lg = tile*64 + l2;
    if (c < RK){
      smem[c*256 + l2] = s;
    } else if (c < RK + NS){
      Bs[(bk*LL + lg)*NS + (c - RK)] = s;
    } else {
      Cs[(bk*LL + lg)*NS + (c - RK - NS)] = s;
    }
  }
  __syncthreads();
  float r0 = smem[0*256 + lsub], r1 = smem[1*256 + lsub], r2 = smem[2*256 + lsub];
  float r3 = smem[3*256 + lsub], r4 = smem[4*256 + lsub], r5 = smem[5*256 + lsub];
  const float* dwb = dt_w + k*DE*RK;
  const float* dbb = dt_b + k*DE;
  for (int dd=0; dd<48; dd++){
    int d = dgrp*48 + dd;
    const float* wr = dwb + d*RK;
    float t = dbb[d];
    t = fmaf(r0, wr[0], t); t = fmaf(r1, wr[1], t); t = fmaf(r2, wr[2], t);
    t = fmaf(r3, wr[3], t); t = fmaf(r4, wr[4], t); t = fmaf(r5, wr[5], t);
    delta[(bk*DE + d)*LL + l] = softplus_f(t);
  }
}

// K4: chunked scan, lane = (chunk c of 64, n-quad q of 4), float4 loads,
// log-space chunk product, LDS-staged coalesced output.
__global__ __launch_bounds__(256) void k4_scan(const float* __restrict__ xconv,
    const float* __restrict__ xconvT,
    const float* __restrict__ delta, const float* __restrict__ Bs,
    const float* __restrict__ Cs, const float* __restrict__ A_logs,
    const float* __restrict__ Ds, float* __restrict__ out_y){
  int gid = blockIdx.x;           // [0, 1536)
  int b = gid / (4*DE);
  int kd = gid % (4*DE);
  int k = kd / DE;
  int d = kd % DE;
  int bk = b*4 + k;
  int tid = threadIdx.x;
  int c = tid >> 2, q = tid & 3;
  const float LOG2E = 1.44269504f;
  float4 al = *(const float4*)&A_logs[(k*DE + d)*NS + q*4];
  float A2[4];
  A2[0] = -__expf(al.x)*LOG2E; A2[1] = -__expf(al.y)*LOG2E;
  A2[2] = -__expf(al.z)*LOG2E; A2[3] = -__expf(al.w)*LOG2E;
  float Dv = Ds[k*DE + d];
  const float* dptr = delta + (bk*DE + d)*LL;
  const float* ub = ((k & 1) ? xconvT : xconv) + (b*DE + d)*LL;
  bool rev = (k >= 2);
  const float* bbase = Bs + bk*LL*NS + q*4;
  const float* cbase = Cs + bk*LL*NS + q*4;
  float* optr = out_y + (bk*DE + d)*LL;
  int l0 = c*CL4;
  // Phase A: local (sumdl, S) per chunk;  P = exp2(A2 * sumdl)
  float sumdl = 0.f, S[4] = {0.f,0.f,0.f,0.f};
  #pragma unroll 3
  for (int i=0;i<CL4;i+=4){
    int l = l0 + i;
    float4 dl4 = *(const float4*)(dptr + l);
    float4 u4;
    if (!rev) u4 = *(const float4*)(ub + l);
    else { float4 t = *(const float4*)(ub + (LL-4) - l); u4 = make_float4(t.w,t.z,t.y,t.x); }
    #pragma unroll
    for (int j=0;j<4;j++){
      float dlj = (j==0)?dl4.x:((j==1)?dl4.y:((j==2)?dl4.z:dl4.w));
      float uj  = (j==0)?u4.x:((j==1)?u4.y:((j==2)?u4.z:u4.w));
      float du = dlj*uj;
      sumdl += dlj;
      float4 Bv = *(const float4*)(bbase + (l+j)*NS);
      float dA0 = exp2f(dlj*A2[0]); S[0] = fmaf(S[0], dA0, du*Bv.x);
      float dA1 = exp2f(dlj*A2[1]); S[1] = fmaf(S[1], dA1, du*Bv.y);
      float dA2 = exp2f(dlj*A2[2]); S[2] = fmaf(S[2], dA2, du*Bv.z);
      float dA3 = exp2f(dlj*A2[3]); S[3] = fmaf(S[3], dA3, du*Bv.w);
    }
  }
  __shared__ float sP[CH4][NS], sS[CH4][NS];
  __shared__ float oy[LL];   // 9.2 KB output stage
  *(float4*)&sP[c][q*4] = make_float4(exp2f(A2[0]*sumdl), exp2f(A2[1]*sumdl),
                                      exp2f(A2[2]*sumdl), exp2f(A2[3]*sumdl));
  *(float4*)&sS[c][q*4] = make_float4(S[0],S[1],S[2],S[3]);
  __syncthreads();
  // Phase B: 16 threads, serial combine over 64 chunks (chain is 64 fma; loads batch)
  if (tid < NS){
    float hacc = 0.f;
    #pragma unroll 4
    for (int cc=0; cc<CH4; cc++){
      hacc = fmaf(hacc, sP[cc][tid], sS[cc][tid]);
      sS[cc][tid] = hacc;
    }
  }
  __syncthreads();
  float h[4];
  if (c == 0){ h[0]=h[1]=h[2]=h[3]=0.f; }
  else { float4 hi = *(const float4*)&sS[c-1][q*4]; h[0]=hi.x; h[1]=hi.y; h[2]=hi.z; h[3]=hi.w; }
  // Phase C: rescan; stage outputs into LDS at spatial position
  #pragma unroll 3
  for (int i=0;i<CL4;i+=4){
    int l = l0 + i;
    float4 dl4 = *(const float4*)(dptr + l);
    float4 u4;
    if (!rev) u4 = *(const float4*)(ub + l);
    else { float4 t = *(const float4*)(ub + (LL-4) - l); u4 = make_float4(t.w,t.z,t.y,t.x); }
    #pragma unroll
    for (int j=0;j<4;j++){
      float dlj = (j==0)?dl4.x:((j==1)?dl4.y:((j==2)?dl4.z:dl4.w));
      float uj  = (j==0)?u4.x:((j==1)?u4.y:((j==2)?u4.z:u4.w));
      float du = dlj*uj;
      float4 Bv = *(const float4*)(bbase + (l+j)*NS);
      float4 Cv = *(const float4*)(cbase + (l+j)*NS);
      float dA0 = exp2f(dlj*A2[0]); h[0] = fmaf(h[0], dA0, du*Bv.x);
      float dA1 = exp2f(dlj*A2[1]); h[1] = fmaf(h[1], dA1, du*Bv.y);
      float dA2 = exp2f(dlj*A2[2]); h[2] = fmaf(h[2], dA2, du*Bv.z);
      float dA3 = exp2f(dlj*A2[3]); h[3] = fmaf(h[3], dA3, du*Bv.w);
      float py = h[0]*Cv.x + h[1]*Cv.y + h[2]*Cv.z + h[3]*Cv.w;
      py += __shfl_xor(py, 1);
      py += __shfl_xor(py, 2);
      if (q == 0){
        oy[dir_map(k, l+j)] = fmaf(Dv, uj, py);
      }
    }
  }
  __syncthreads();
  // coalesced float4 flush
  {
    float4* o4 = (float4*)optr;
    const float4* s4 = (const float4*)oy;
    for (int i = tid; i < LL/4; i += 256) o4[i] = s4[i];
  }
}

// K5: combine 4 dirs + channel LN; also emit per-tile channel partial sums.
__global__ __launch_bounds__(256) void k5_combine_ln(const float* __restrict__ out_y,
    const float* __restrict__ onw, const float* __restrict__ onb,
    float* __restrict__ y_ln, float* __restrict__ partial){
  __shared__ float vals[DE][17];
  __shared__ float s_[16][16], s2_[16][16];
  __shared__ float mu_[16], rs_[16];
  int bT = blockIdx.x;               // [0, 288) = b*144 + tile
  int b = bT / 144;
  int pos0 = (bT % 144) * 16;
  int tid = threadIdx.x;
  int p = tid & 15, g = tid >> 4;
  const float* base = out_y + b*4*DE*LL;
  float s = 0.f, s2 = 0.f;
  #pragma unroll
  for (int j=0;j<12;j++){
    int d = g*12 + j;
    int idx = d*LL + pos0 + p;
    float v = base[idx] + base[DE*LL + idx] + base[2*DE*LL + idx] + base[3*DE*LL + idx];
    vals[d][p] = v;
    s += v; s2 += v*v;
  }
  s_[g][p] = s; s2_[g][p] = s2;
  __syncthreads();
  if (tid < 16){
    float ss = 0.f, ss2 = 0.f;
    #pragma unroll
    for (int gg=0; gg<16; gg++){ ss += s_[gg][tid]; ss2 += s2_[gg][tid]; }
    float mu = ss / DE;
    float var = ss2 / DE - mu*mu;
    mu_[tid] = mu; rs_[tid] = rsqrtf(var + 1e-5f);
  }
  __syncthreads();
  float mu = mu_[p], rs = rs_[p];
  #pragma unroll
  for (int j=0;j<12;j++){
    int d = g*12 + j;
    float yv = (vals[d][p] - mu)*rs*onw[d] + onb[d];
    y_ln[(b*DE + d)*LL + pos0 + p] = yv;
    vals[d][p] = yv;
  }
  __syncthreads();
  if (tid < DE){
    float ps = 0.f;
    #pragma unroll
    for (int pp=0;pp<16;pp++) ps += vals[tid][pp];
    partial[bT*DE + tid] = ps;
  }
}

// K6b: channel core, chunked scan. grid=2 (one block per b), 512 threads.
__global__ __launch_bounds__(512) void k6b_channel(const float* __restrict__ partial,
    const float* __restrict__ cin_w, const float* __restrict__ cin_b,
    const float* __restrict__ cout_w, const float* __restrict__ cout_b,
    const float* __restrict__ xc_proj_w, const float* __restrict__ dtc_w,
    const float* __restrict__ dtc_b, const float* __restrict__ Ac_logs,
    const float* __restrict__ Dsc, const float* __restrict__ cn_w,
    const float* __restrict__ cn_b, float* __restrict__ cvec){
  __shared__ float xcs[DE];
  __shared__ float tmp[384];
  __shared__ float sP[128][4], sS[128][4];
  __shared__ float outc[2][4][DE];
  __shared__ float ycs[DE];
  __shared__ float muS, rsS;
  int b = blockIdx.x;
  int tid = threadIdx.x;
  if (tid < 384){
    int d = tid % DE, half = tid / DE;
    const float* pp = partial + (b*144 + half*72)*DE + d;
    float sacc = 0.f;
    #pragma unroll 8
    for (int t=0;t<72;t++) sacc += pp[t*DE];
    tmp[tid] = sacc;
  }
  __syncthreads();
  if (tid < DE) xcs[tid] = (tmp[tid] + tmp[tid + DE]) * (1.f/LL);
  __syncthreads();
  int chain = tid >> 2, ch = tid & 3;
  int k = chain >> 6, dc = (chain >> 4) & 3, n = chain & 15;
  const float LOG2E = 1.44269504f;
  float EW0=0,EW1=0,EW2=0,EW3=0;
  #pragma unroll
  for (int r=0;r<RK;r++){
    float dw = dtc_w[(k*4+dc)*RK + r];
    EW0 = fmaf(dw, xc_proj_w[(k*NC + r)*4 + 0], EW0);
    EW1 = fmaf(dw, xc_proj_w[(k*NC + r)*4 + 1], EW1);
    EW2 = fmaf(dw, xc_proj_w[(k*NC + r)*4 + 2], EW2);
    EW3 = fmaf(dw, xc_proj_w[(k*NC + r)*4 + 3], EW3);
  }
  float Bw0 = xc_proj_w[(k*NC + RK + n)*4 + 0];
  float Bw1 = xc_proj_w[(k*NC + RK + n)*4 + 1];
  float Bw2 = xc_proj_w[(k*NC + RK + n)*4 + 2];
  float Bw3 = xc_proj_w[(k*NC + RK + n)*4 + 3];
  float Cw0 = xc_proj_w[(k*NC + RK + NS + n)*4 + 0];
  float Cw1 = xc_proj_w[(k*NC + RK + NS + n)*4 + 1];
  float Cw2 = xc_proj_w[(k*NC + RK + NS + n)*4 + 2];
  float Cw3 = xc_proj_w[(k*NC + RK + NS + n)*4 + 3];
  float A2 = -__expf(Ac_logs[(k*4+dc)*NS + n]) * LOG2E;
  float Dv = Dsc[k*4+dc];
  float dtb = dtc_b[k*4+dc];
  float ciw0=cin_w[0], ciw1=cin_w[1], ciw2=cin_w[2], ciw3=cin_w[3];
  float cib0=cin_b[0], cib1=cin_b[1], cib2=cin_b[2], cib3=cin_b[3];
  int l0 = ch*48;
  float P = 1.f, S = 0.f;
  for (int i=0;i<48;i++){
    int lc = l0 + i;
    int lp = k ? (191 - lc) : lc;
    float xv = xcs[lp];
    float xs0 = fmaf(xv, ciw0, cib0);
    float xs1 = fmaf(xv, ciw1, cib1);
    float xs2 = fmaf(xv, ciw2, cib2);
    float xs3 = fmaf(xv, ciw3, cib3);
    float dt = dtb + xs0*EW0 + xs1*EW1 + xs2*EW2 + xs3*EW3;
    float dl = softplus_f(dt);
    float Bv = xs0*Bw0 + xs1*Bw1 + xs2*Bw2 + xs3*Bw3;
    float u = (dc==0)?xs0:((dc==1)?xs1:((dc==2)?xs2:xs3));
    float dA = exp2f(dl * A2);
    S = fmaf(S, dA, dl*u*Bv);
    P *= dA;
  }
  sP[chain][ch] = P; sS[chain][ch] = S;
  __syncthreads();
  if (tid < 128){
    float hacc = 0.f;
    #pragma unroll
    for (int cc=0; cc<4; cc++){
      hacc = fmaf(hacc, sP[tid][cc], sS[tid][cc]);
      sS[tid][cc] = hacc;
    }
  }
  __syncthreads();
  float h = (ch == 0) ? 0.f : sS[chain][ch-1];
  for (int i=0;i<48;i++){
    int lc = l0 + i;
    int lp = k ? (191 - lc) : lc;
    float xv = xcs[lp];
    float xs0 = fmaf(xv, ciw0, cib0);
    float xs1 = fmaf(xv, ciw1, cib1);
    float xs2 = fmaf(xv, ciw2, cib2);
    float xs3 = fmaf(xv, ciw3, cib3);
    float dt = dtb + xs0*EW0 + xs1*EW1 + xs2*EW2 + xs3*EW3;
    float dl = softplus_f(dt);
    float Bv = xs0*Bw0 + xs1*Bw1 + xs2*Bw2 + xs3*Bw3;
    float Cv = xs0*Cw0 + xs1*Cw1 + xs2*Cw2 + xs3*Cw3;
    float u = (dc==0)?xs0:((dc==1)?xs1:((dc==2)?xs2:xs3));
    float dA = exp2f(dl * A2);
    h = fmaf(h, dA, dl*u*Bv);
    float py = h * Cv;
    py += __shfl_xor(py, 4);
    py += __shfl_xor(py, 8);
    py += __shfl_xor(py, 16);
    py += __shfl_xor(py, 32);
    if (n == 0) outc[k][dc][lc] = fmaf(Dv, u, py);
  }
  __syncthreads();
  float co0=cout_w[0], co1=cout_w[1], co2=cout_w[2], co3=cout_w[3], cob=cout_b[0];
  for (int i = tid; i < DE; i += 512){
    float yv = cob
      + co0*(outc[0][0][i] + outc[1][0][191-i])
      + co1*(outc[0][1][i] + outc[1][1][191-i])
      + co2*(outc[0][2][i] + outc[1][2][191-i])
      + co3*(outc[0][3][i] + outc[1][3][191-i]);
    ycs[i] = yv;
  }
  __syncthreads();
  if (tid < 64){
    float s = 0.f, s2 = 0.f;
    #pragma unroll
    for (int j=0;j<3;j++){
      float v = ycs[tid + j*64];
      s += v; s2 += v*v;
    }
    for (int off=32; off>0; off>>=1){ s += __shfl_down(s, off); s2 += __shfl_down(s2, off); }
    if (tid == 0){
      float mu = s / DE;
      float var = s2 / DE - mu*mu;
      muS = mu; rsS = rsqrtf(var + 1e-5f);
    }
  }
  __syncthreads();
  float mu = muS, rs = rsS;
  for (int i = tid; i < DE; i += 512){
    cvec[b*DE + i] = (ycs[i] - mu) * rs * cn_w[i] + cn_b[i];
  }
}

// K7: out = conv1x1(y_ln * c * z), 192 -> 96
__global__ __launch_bounds__(256) void k7_out(const float* __restrict__ y_ln,
    const float* __restrict__ cvec, const float* __restrict__ z,
    const float* __restrict__ out_w, const float* __restrict__ out_b,
    float* __restrict__ outp){
  __shared__ float t[DE*16];
  int tile = blockIdx.x;
  int b = tile / 144;
  int pos0 = (tile % 144) * 16;
  int tid = threadIdx.x;
  for (int i = tid; i < DE*4; i += 256){
    int c = i >> 2, p4 = (i & 3)*4;
    int gi = (b*DE + c)*LL + pos0 + p4;
    float4 yv = *(const float4*)(y_ln + gi);
    float4 zv = *(const float4*)(z + gi);
    float cv = cvec[b*DE + c];
    *(float4*)&t[c*16 + p4] = make_float4(yv.x*cv*zv.x, yv.y*cv*zv.y, yv.z*cv*zv.z, yv.w*cv*zv.w);
  }
  __syncthreads();
  for (int j = tid; j < DM*16; j += 256){
    int o = j >> 4, p = j & 15;
    float acc = out_b[o];
    const float4* wr4 = (const float4*)(out_w + o*DE);
    #pragma unroll 8
    for (int c4=0;c4<48;c4++){
      float4 wv = wr4[c4];
      acc = fmaf(wv.x, t[(c4*4+0)*16+p], acc);
      acc = fmaf(wv.y, t[(c4*4+1)*16+p], acc);
      acc = fmaf(wv.z, t[(c4*4+2)*16+p], acc);
      acc = fmaf(wv.w, t[(c4*4+3)*16+p], acc);
    }
    outp[(b*DM + o)*LL + pos0 + p] = acc;
  }
}

extern "C" void kernel_launch(void* const* d_in, const int* in_sizes, int n_in,
                              void* d_out, int out_size, void* d_ws, size_t ws_size,
                              hipStream_t stream){
  const float* x        = (const float*)d_in[0];
  const float* in_w     = (const float*)d_in[1];
  const float* in_b     = (const float*)d_in[2];
  const float* dw_w     = (const float*)d_in[3];
  const float* dw_b     = (const float*)d_in[4];
  const float* x_proj_w = (const float*)d_in[5];
  const float* dt_w     = (const float*)d_in[6];
  const float* dt_b     = (const float*)d_in[7];
  const float* A_logs   = (const float*)d_in[8];
  const float* Ds       = (const float*)d_in[9];
  const float* onw      = (const float*)d_in[10];
  const float* onb      = (const float*)d_in[11];
  const float* cin_w    = (const float*)d_in[12];
  const float* cin_b    = (const float*)d_in[13];
  const float* cout_w   = (const float*)d_in[14];
  const float* cout_b   = (const float*)d_in[15];
  const float* xc_proj_w= (const float*)d_in[16];
  const float* dtc_w    = (const float*)d_in[17];
  const float* dtc_b    = (const float*)d_in[18];
  const float* Ac_logs  = (const float*)d_in[19];
  const float* Dsc      = (const float*)d_in[20];
  const float* cn_w     = (const float*)d_in[21];
  const float* cn_b     = (const float*)d_in[22];
  const float* out_w    = (const float*)d_in[23];
  const float* out_b    = (const float*)d_in[24];

  float* ws = (float*)d_ws;
  float* x1raw = ws;  ws += 2*DE*LL;
  float* zbuf  = ws;  ws += 2*DE*LL;
  float* xconv = ws;  ws += 2*DE*LL;
  float* delta = ws;  ws += 2*4*DE*LL;
  float* Bsb   = ws;  ws += 2*4*LL*NS;
  float* Csb   = ws;  ws += 2*4*LL*NS;
  float* outy  = ws;  ws += 2*4*DE*LL;
  float* yln   = ws;  ws += 2*DE*LL;
  float* cvec  = ws;  ws += 2*DE;
  float* partial = ws; ws += 2*144*DE;
  float* xconvT = yln;   // alias: xconvT dead before k5 writes yln

  hipLaunchKernelGGL(k1_conv_in, dim3(288), dim3(384), 0, stream, x, in_w, in_b, x1raw, zbuf);
  hipLaunchKernelGGL(k2_dwconv, dim3(384), dim3(256), 0, stream, x1raw, dw_w, dw_b, xconv, xconvT);
  hipLaunchKernelGGL(k3_proj, dim3(288), dim3(256), 0, stream, xconv, xconvT, x_proj_w, dt_w, dt_b, delta, Bsb, Csb);
  hipLaunchKernelGGL(k4_scan, dim3(1536), dim3(256), 0, stream, xconv, xconvT, delta, Bsb, Csb, A_logs, Ds, outy);
  hipLaunchKernelGGL(k5_combine_ln, dim3(288), dim3(256), 0, stream, outy, onw, onb, yln, partial);
  hipLaunchKernelGGL(k6b_channel, dim3(2), dim3(512), 0, stream, partial, cin_w, cin_b, cout_w, cout_b,
                     xc_proj_w, dtc_w, dtc_b, Ac_logs, Dsc, cn_w, cn_b, cvec);
  hipLaunchKernelGGL(k7_out, dim3(288), dim3(256), 0, stream, yln, cvec, zbuf, out_w, out_b, (float*)d_out);
}